// Round 10
// baseline (221.652 us; speedup 1.0000x reference)
//
#include <hip/hip_runtime.h>
#include <hip/hip_fp16.h>
#include <math.h>

constexpr int SCAN_TPB = 256;
constexpr int SCAN_EPT = 8;                      // elements per thread
constexpr int SCAN_EPB = SCAN_TPB * SCAN_EPT;    // 2048 per block

// ---------------- degree (in-degree over dst) ----------------
__global__ void k_deg(const int* __restrict__ dst, int* __restrict__ deg, int E) {
    int i = blockIdx.x * blockDim.x + threadIdx.x;
    if (i < E) atomicAdd(&deg[dst[i]], 1);
}

// ---------------- scan phase A: per-block sums ----------------
__global__ __launch_bounds__(SCAN_TPB) void k_blocksum(const int* __restrict__ deg,
                                                       int* __restrict__ bsum, int n) {
    int t = threadIdx.x;
    int idx0 = blockIdx.x * SCAN_EPB + t * SCAN_EPT;
    int s = 0;
    if (idx0 + SCAN_EPT <= n) {
        const int4* p = reinterpret_cast<const int4*>(deg + idx0);
        int4 a = p[0], b = p[1];
        s = a.x + a.y + a.z + a.w + b.x + b.y + b.z + b.w;
    } else {
        for (int k = 0; k < SCAN_EPT; ++k) { int i = idx0 + k; if (i < n) s += deg[i]; }
    }
#pragma unroll
    for (int off = 32; off; off >>= 1) s += __shfl_xor(s, off);
    __shared__ int wsum[4];
    int lane = t & 63, wid = t >> 6;
    if (lane == 0) wsum[wid] = s;
    __syncthreads();
    if (t == 0) bsum[blockIdx.x] = wsum[0] + wsum[1] + wsum[2] + wsum[3];
}

// ---------------- scan phase B: exclusive-scan the block sums (tiny) ----------------
__global__ __launch_bounds__(256) void k_scanbsum(int* __restrict__ bsum,
                                                  int* __restrict__ row_off, int nb, int n) {
    int t = threadIdx.x, lane = t & 63, wid = t >> 6;
    __shared__ int wsum[4];
    int carry = 0;
    for (int base = 0; base < nb; base += 256) {
        int i = base + t;
        int v = (i < nb) ? bsum[i] : 0;
        int s = v;
#pragma unroll
        for (int off = 1; off < 64; off <<= 1) { int u = __shfl_up(s, off); if (lane >= off) s += u; }
        if (lane == 63) wsum[wid] = s;
        __syncthreads();
        int add = carry;
        for (int w = 0; w < wid; ++w) add += wsum[w];
        if (i < nb) bsum[i] = s - v + add;        // exclusive + carry
        carry += wsum[0] + wsum[1] + wsum[2] + wsum[3];
        __syncthreads();
    }
    if (t == 0) row_off[n] = carry;               // total edge count
}

// ---------------- scan phase C: final scan, write row_off + cursor ----------------
__global__ __launch_bounds__(SCAN_TPB) void k_scanfinal(const int* __restrict__ deg,
                                                        const int* __restrict__ bsum,
                                                        int* __restrict__ row_off,
                                                        int* __restrict__ cursor, int n) {
    int t = threadIdx.x, lane = t & 63, wid = t >> 6;
    int idx0 = blockIdx.x * SCAN_EPB + t * SCAN_EPT;
    int e[SCAN_EPT];
    bool full = (idx0 + SCAN_EPT <= n);
    if (full) {
        const int4* p = reinterpret_cast<const int4*>(deg + idx0);
        int4 a = p[0], b = p[1];
        e[0] = a.x; e[1] = a.y; e[2] = a.z; e[3] = a.w;
        e[4] = b.x; e[5] = b.y; e[6] = b.z; e[7] = b.w;
    } else {
        for (int k = 0; k < SCAN_EPT; ++k) { int i = idx0 + k; e[k] = (i < n) ? deg[i] : 0; }
    }
    int tsum = 0;
#pragma unroll
    for (int k = 0; k < SCAN_EPT; ++k) tsum += e[k];
    int s = tsum;
#pragma unroll
    for (int off = 1; off < 64; off <<= 1) { int u = __shfl_up(s, off); if (lane >= off) s += u; }
    __shared__ int wsum[4];
    if (lane == 63) wsum[wid] = s;
    __syncthreads();
    int add = bsum[blockIdx.x];
    for (int w = 0; w < wid; ++w) add += wsum[w];
    int run = s - tsum + add;                     // thread's exclusive prefix
    int o[SCAN_EPT];
#pragma unroll
    for (int k = 0; k < SCAN_EPT; ++k) { o[k] = run; run += e[k]; }
    if (full) {
        int4* ro = reinterpret_cast<int4*>(row_off + idx0);
        int4* cu = reinterpret_cast<int4*>(cursor + idx0);
        ro[0] = make_int4(o[0], o[1], o[2], o[3]);
        ro[1] = make_int4(o[4], o[5], o[6], o[7]);
        cu[0] = make_int4(o[0], o[1], o[2], o[3]);
        cu[1] = make_int4(o[4], o[5], o[6], o[7]);
    } else {
        for (int k = 0; k < SCAN_EPT; ++k) {
            int i = idx0 + k;
            if (i < n) { row_off[i] = o[k]; cursor[i] = o[k]; }
        }
    }
}

// ---------------- dinv + pre-scaled features xsc[i] = x[i]*dinv[i] ----------------
__global__ void k_dinvx(const int* __restrict__ deg, const float* __restrict__ x,
                        float* __restrict__ dinv, float2* __restrict__ xsc, int n) {
    int i = blockIdx.x * blockDim.x + threadIdx.x;
    if (i < n) {
        float di = rsqrtf((float)deg[i] + 1.0f);  // +1 self loop, always > 0
        dinv[i] = di;
        xsc[i] = make_float2(x[2 * i] * di, x[2 * i + 1] * di);
    }
}

// ---------------- CSR fill (counting sort by dst) ----------------
__global__ void k_fill(const int* __restrict__ src, const int* __restrict__ dst,
                       int* __restrict__ cursor, int* __restrict__ csr_src, int E) {
    int e = blockIdx.x * blockDim.x + threadIdx.x;
    if (e < E) {
        int pos = atomicAdd(&cursor[dst[e]], 1);
        csr_src[pos] = src[e];
    }
}

// ---------------- layer-1 sparse aggregation: xam[i] = dinv[i]*(xsc[i] + sum_nbr xsc[s])
__global__ __launch_bounds__(256) void k_agg1(
    const float2* __restrict__ xsc, const float* __restrict__ dinv,
    const int* __restrict__ row_off, const int* __restrict__ csr_src,
    float2* __restrict__ xam, int n) {
    int i = blockIdx.x * blockDim.x + threadIdx.x;
    if (i >= n) return;
    int r0 = row_off[i], r1 = row_off[i + 1];
    float2 self = xsc[i];
    float xa0 = self.x, xa1 = self.y;
    for (int j = r0; j < r1; ++j) {
        float2 v = xsc[csr_src[j]];               // 8B gather, xsc=1.6MB L2-resident
        xa0 += v.x; xa1 += v.y;
    }
    float di = dinv[i];
    xam[i] = make_float2(xa0 * di, xa1 * di);
}

// ---------------- layer-1 dense part: m2[i] = relu(xam[i]@W1+b1)@W2 * dinv[i]
// Rounds 8/9 lesson: any per-thread acc[>16] gets strip-mined by the compiler
// (acc64->VGPR40, acc32->VGPR20), serializing k-loop passes. Design to acc[16]:
// grid.y = 4 feature-quarters (q = blockIdx.y, provably SGPR -> W2 s_loads
// stay scalar). ~40 VGPR -> 8 waves/SIMD hides the W2 K$-miss latency.
// m2 stored as fp16 (halves k_l2out's random-gather traffic; err 5e-4 rel).
__global__ __launch_bounds__(256) void k_gemm1(
    const float2* __restrict__ xam, const float* __restrict__ dinv,
    const float* __restrict__ W1, const float* __restrict__ b1,
    const float* __restrict__ W2, __half* __restrict__ m2h, int n) {
    int q = blockIdx.y;                            // feature quarter 0..3 (SGPR)
    int i = blockIdx.x * 256 + threadIdx.x;
    if (i >= n) return;
    float2 xa = xam[i];
    float acc[16];
#pragma unroll
    for (int f = 0; f < 16; ++f) acc[f] = 0.f;
#pragma unroll 1
    for (int k = 0; k < 128; ++k) {                // one 16-float W2 slice/iter (dwordx16)
        float h = fmaxf(fmaf(xa.y, W1[128 + k], fmaf(xa.x, W1[k], b1[k])), 0.f);
        const float* w2row = &W2[k * 64 + q * 16]; // wave-uniform -> s_load
#pragma unroll
        for (int f = 0; f < 16; ++f) acc[f] = fmaf(h, w2row[f], acc[f]);
    }
    float di = dinv[i];
    union { __half2 h2[8]; int4 q4[2]; } u;
#pragma unroll
    for (int f2 = 0; f2 < 8; ++f2)
        u.h2[f2] = __floats2half2_rn(acc[2 * f2] * di, acc[2 * f2 + 1] * di);
    int4* mo = reinterpret_cast<int4*>(m2h + (size_t)i * 64 + q * 16);
    mo[0] = u.q4[0]; mo[1] = u.q4[1];
}

// ---------------- layer 2 gather + full epilogue, one wave per node ----------------
// fp16 m2 rows = 128B. lane = (edge_slot[0..7], f8[0..7]): 8 edge rows in
// flight per iteration; deg<=7 nodes finish the gather in ONE iteration.
__global__ __launch_bounds__(256) void k_l2out(
    const __half* __restrict__ m2h, const float* __restrict__ dinv,
    const int* __restrict__ row_off, const int* __restrict__ csr_src,
    const float* __restrict__ b2, const float* __restrict__ Wp,
    const float* __restrict__ bp, float* __restrict__ out, int n) {
    int tid = threadIdx.x;
    int wid = tid >> 6, lane = tid & 63;
    int es = lane >> 3;                            // edge slot 0..7
    int f8 = lane & 7;                             // feature octet 0..7
    int i = blockIdx.x * 4 + wid;
    if (i >= n) return;
    int r0 = row_off[i], r1 = row_off[i + 1];
    int cnt = r1 - r0 + 1;                         // neighbors + self
    float a[8];
#pragma unroll
    for (int j = 0; j < 8; ++j) a[j] = 0.f;
    for (int e = es; e < cnt; e += 8) {            // 8 edges in flight across slots
        int s = (e == 0) ? i : csr_src[r0 + e - 1];
        int4 v = *reinterpret_cast<const int4*>(m2h + (size_t)s * 64 + f8 * 8);
        const __half2* hv = reinterpret_cast<const __half2*>(&v);
#pragma unroll
        for (int j = 0; j < 4; ++j) {
            float2 f2 = __half22float2(hv[j]);
            a[2 * j] += f2.x; a[2 * j + 1] += f2.y;
        }
    }
#pragma unroll
    for (int off = 8; off < 64; off <<= 1) {       // reduce 8 edge slots (bits 3..5)
#pragma unroll
        for (int j = 0; j < 8; ++j) a[j] += __shfl_xor(a[j], off);
    }
    float di = dinv[i];
    float4 b2a = reinterpret_cast<const float4*>(b2)[f8 * 2];
    float4 b2b = reinterpret_cast<const float4*>(b2)[f8 * 2 + 1];
    float4 wpa = reinterpret_cast<const float4*>(Wp)[f8 * 2];
    float4 wpb = reinterpret_cast<const float4*>(Wp)[f8 * 2 + 1];
    float v = fmaxf(fmaf(a[0], di, b2a.x), 0.f) * wpa.x
            + fmaxf(fmaf(a[1], di, b2a.y), 0.f) * wpa.y
            + fmaxf(fmaf(a[2], di, b2a.z), 0.f) * wpa.z
            + fmaxf(fmaf(a[3], di, b2a.w), 0.f) * wpa.w
            + fmaxf(fmaf(a[4], di, b2b.x), 0.f) * wpb.x
            + fmaxf(fmaf(a[5], di, b2b.y), 0.f) * wpb.y
            + fmaxf(fmaf(a[6], di, b2b.z), 0.f) * wpb.z
            + fmaxf(fmaf(a[7], di, b2b.w), 0.f) * wpb.w;
#pragma unroll
    for (int off = 1; off < 8; off <<= 1) v += __shfl_xor(v, off);  // reduce f8 groups
    if (lane == 0) out[i] = 1.f / (1.f + expf(-(v + bp[0])));
}

extern "C" void kernel_launch(void* const* d_in, const int* in_sizes, int n_in,
                              void* d_out, int out_size, void* d_ws, size_t ws_size,
                              hipStream_t stream) {
    const float* x  = (const float*)d_in[0];
    const int*   ei = (const int*)d_in[1];   // [2, E] int32
    const float* W1 = (const float*)d_in[2];
    const float* b1 = (const float*)d_in[3];
    const float* W2 = (const float*)d_in[4];
    const float* b2 = (const float*)d_in[5];
    const float* Wp = (const float*)d_in[6];
    const float* bp = (const float*)d_in[7];
    float* out = (float*)d_out;

    int n = in_sizes[0] / 2;
    int E = in_sizes[1] / 2;
    const int* src = ei;
    const int* dst = ei + E;

    char* ws = (char*)d_ws;
    size_t off = 0;
    auto alloc = [&](size_t bytes) -> void* {
        void* p = ws + off;
        off += (bytes + 255) & ~(size_t)255;
        return p;
    };
    int nb = (n + SCAN_EPB - 1) / SCAN_EPB;
    int*    deg     = (int*)alloc((size_t)n * 4);
    int*    bsum    = (int*)alloc((size_t)nb * 4);
    int*    row_off = (int*)alloc((size_t)(n + 1) * 4);
    int*    cursor  = (int*)alloc((size_t)n * 4);
    float*  dinv    = (float*)alloc((size_t)n * 4);
    float2* xsc     = (float2*)alloc((size_t)n * 8);
    float2* xam     = (float2*)alloc((size_t)n * 8);
    int*    csr_src = (int*)alloc((size_t)E * 4);
    __half* m2h     = (__half*)alloc((size_t)n * 64 * 2);
    (void)ws_size;

    hipMemsetAsync(deg, 0, (size_t)n * 4, stream);
    k_deg      <<<(E + 255) / 256, 256, 0, stream>>>(dst, deg, E);
    k_blocksum <<<nb, SCAN_TPB, 0, stream>>>(deg, bsum, n);
    k_scanbsum <<<1, 256, 0, stream>>>(bsum, row_off, nb, n);
    k_scanfinal<<<nb, SCAN_TPB, 0, stream>>>(deg, bsum, row_off, cursor, n);
    k_dinvx    <<<(n + 255) / 256, 256, 0, stream>>>(deg, x, dinv, xsc, n);
    k_fill     <<<(E + 255) / 256, 256, 0, stream>>>(src, dst, cursor, csr_src, E);
    k_agg1     <<<(n + 255) / 256, 256, 0, stream>>>(xsc, dinv, row_off, csr_src, xam, n);
    dim3 ggrid((n + 255) / 256, 4);
    k_gemm1    <<<ggrid, 256, 0, stream>>>(xam, dinv, W1, b1, W2, m2h, n);
    k_l2out    <<<(n + 3) / 4, 256, 0, stream>>>(m2h, dinv, row_off, csr_src,
                                                 b2, Wp, bp, out, n);
}

// Round 11
// 221.013 us; speedup vs baseline: 1.0029x; 1.0029x over previous
//
#include <hip/hip_runtime.h>
#include <hip/hip_fp16.h>
#include <math.h>

constexpr int SCAN_TPB = 256;
constexpr int SCAN_EPT = 8;                      // elements per thread
constexpr int SCAN_EPB = SCAN_TPB * SCAN_EPT;    // 2048 per block

// ---------------- degree (in-degree over dst) ----------------
__global__ void k_deg(const int* __restrict__ dst, int* __restrict__ deg, int E) {
    int i = blockIdx.x * blockDim.x + threadIdx.x;
    if (i < E) atomicAdd(&deg[dst[i]], 1);
}

// ---------------- scan phase A: per-block sums ----------------
__global__ __launch_bounds__(SCAN_TPB) void k_blocksum(const int* __restrict__ deg,
                                                       int* __restrict__ bsum, int n) {
    int t = threadIdx.x;
    int idx0 = blockIdx.x * SCAN_EPB + t * SCAN_EPT;
    int s = 0;
    if (idx0 + SCAN_EPT <= n) {
        const int4* p = reinterpret_cast<const int4*>(deg + idx0);
        int4 a = p[0], b = p[1];
        s = a.x + a.y + a.z + a.w + b.x + b.y + b.z + b.w;
    } else {
        for (int k = 0; k < SCAN_EPT; ++k) { int i = idx0 + k; if (i < n) s += deg[i]; }
    }
#pragma unroll
    for (int off = 32; off; off >>= 1) s += __shfl_xor(s, off);
    __shared__ int wsum[4];
    int lane = t & 63, wid = t >> 6;
    if (lane == 0) wsum[wid] = s;
    __syncthreads();
    if (t == 0) bsum[blockIdx.x] = wsum[0] + wsum[1] + wsum[2] + wsum[3];
}

// ---------------- scan phase B: exclusive-scan the block sums (tiny) ----------------
__global__ __launch_bounds__(256) void k_scanbsum(int* __restrict__ bsum,
                                                  int* __restrict__ row_off, int nb, int n) {
    int t = threadIdx.x, lane = t & 63, wid = t >> 6;
    __shared__ int wsum[4];
    int carry = 0;
    for (int base = 0; base < nb; base += 256) {
        int i = base + t;
        int v = (i < nb) ? bsum[i] : 0;
        int s = v;
#pragma unroll
        for (int off = 1; off < 64; off <<= 1) { int u = __shfl_up(s, off); if (lane >= off) s += u; }
        if (lane == 63) wsum[wid] = s;
        __syncthreads();
        int add = carry;
        for (int w = 0; w < wid; ++w) add += wsum[w];
        if (i < nb) bsum[i] = s - v + add;        // exclusive + carry
        carry += wsum[0] + wsum[1] + wsum[2] + wsum[3];
        __syncthreads();
    }
    if (t == 0) row_off[n] = carry;               // total edge count
}

// ---------------- scan phase C: final scan, write row_off + cursor ----------------
__global__ __launch_bounds__(SCAN_TPB) void k_scanfinal(const int* __restrict__ deg,
                                                        const int* __restrict__ bsum,
                                                        int* __restrict__ row_off,
                                                        int* __restrict__ cursor, int n) {
    int t = threadIdx.x, lane = t & 63, wid = t >> 6;
    int idx0 = blockIdx.x * SCAN_EPB + t * SCAN_EPT;
    int e[SCAN_EPT];
    bool full = (idx0 + SCAN_EPT <= n);
    if (full) {
        const int4* p = reinterpret_cast<const int4*>(deg + idx0);
        int4 a = p[0], b = p[1];
        e[0] = a.x; e[1] = a.y; e[2] = a.z; e[3] = a.w;
        e[4] = b.x; e[5] = b.y; e[6] = b.z; e[7] = b.w;
    } else {
        for (int k = 0; k < SCAN_EPT; ++k) { int i = idx0 + k; e[k] = (i < n) ? deg[i] : 0; }
    }
    int tsum = 0;
#pragma unroll
    for (int k = 0; k < SCAN_EPT; ++k) tsum += e[k];
    int s = tsum;
#pragma unroll
    for (int off = 1; off < 64; off <<= 1) { int u = __shfl_up(s, off); if (lane >= off) s += u; }
    __shared__ int wsum[4];
    if (lane == 63) wsum[wid] = s;
    __syncthreads();
    int add = bsum[blockIdx.x];
    for (int w = 0; w < wid; ++w) add += wsum[w];
    int run = s - tsum + add;                     // thread's exclusive prefix
    int o[SCAN_EPT];
#pragma unroll
    for (int k = 0; k < SCAN_EPT; ++k) { o[k] = run; run += e[k]; }
    if (full) {
        int4* ro = reinterpret_cast<int4*>(row_off + idx0);
        int4* cu = reinterpret_cast<int4*>(cursor + idx0);
        ro[0] = make_int4(o[0], o[1], o[2], o[3]);
        ro[1] = make_int4(o[4], o[5], o[6], o[7]);
        cu[0] = make_int4(o[0], o[1], o[2], o[3]);
        cu[1] = make_int4(o[4], o[5], o[6], o[7]);
    } else {
        for (int k = 0; k < SCAN_EPT; ++k) {
            int i = idx0 + k;
            if (i < n) { row_off[i] = o[k]; cursor[i] = o[k]; }
        }
    }
}

// ---------------- dinv + pre-scaled features xsc[i] = x[i]*dinv[i] ----------------
__global__ void k_dinvx(const int* __restrict__ deg, const float* __restrict__ x,
                        float* __restrict__ dinv, float2* __restrict__ xsc, int n) {
    int i = blockIdx.x * blockDim.x + threadIdx.x;
    if (i < n) {
        float di = rsqrtf((float)deg[i] + 1.0f);  // +1 self loop, always > 0
        dinv[i] = di;
        xsc[i] = make_float2(x[2 * i] * di, x[2 * i + 1] * di);
    }
}

// ---------------- CSR fill (counting sort by dst) ----------------
__global__ void k_fill(const int* __restrict__ src, const int* __restrict__ dst,
                       int* __restrict__ cursor, int* __restrict__ csr_src, int E) {
    int e = blockIdx.x * blockDim.x + threadIdx.x;
    if (e < E) {
        int pos = atomicAdd(&cursor[dst[e]], 1);
        csr_src[pos] = src[e];
    }
}

// ---------------- layer-1 sparse aggregation: xam[i] = dinv[i]*(xsc[i] + sum_nbr xsc[s])
__global__ __launch_bounds__(256) void k_agg1(
    const float2* __restrict__ xsc, const float* __restrict__ dinv,
    const int* __restrict__ row_off, const int* __restrict__ csr_src,
    float2* __restrict__ xam, int n) {
    int i = blockIdx.x * blockDim.x + threadIdx.x;
    if (i >= n) return;
    int r0 = row_off[i], r1 = row_off[i + 1];
    float2 self = xsc[i];
    float xa0 = self.x, xa1 = self.y;
    for (int j = r0; j < r1; ++j) {
        float2 v = xsc[csr_src[j]];               // 8B gather, xsc=1.6MB L2-resident
        xa0 += v.x; xa1 += v.y;
    }
    float di = dinv[i];
    xam[i] = make_float2(xa0 * di, xa1 * di);
}

// ---------------- layer-1 dense part: m2[i] = relu(xam[i]@W1+b1)@W2 * dinv[i]
// Rounds 8/9/10 lesson: the compiler strip-mines/interchanges any multi-acc
// k-loop to shrink registers (acc64->VGPR40, acc32->20, acc16->12 with 4x
// redundant k-passes). Fix: NAMED scalar accumulators + an empty asm volatile
// inside the loop that reads+writes all 16 in VGPRs -> every iteration needs
// all 16 live -> strip-mine/interchange has no register payoff and the
// straight-line schedule survives. Zero instruction cost.
__global__ __launch_bounds__(256) void k_gemm1(
    const float2* __restrict__ xam, const float* __restrict__ dinv,
    const float* __restrict__ W1, const float* __restrict__ b1,
    const float* __restrict__ W2, __half* __restrict__ m2h, int n) {
    int q = blockIdx.y;                            // feature quarter 0..3 (SGPR)
    int i = blockIdx.x * 256 + threadIdx.x;
    if (i >= n) return;
    float2 xa = xam[i];
    float a0 = 0.f, a1 = 0.f, a2 = 0.f, a3 = 0.f, a4 = 0.f, a5 = 0.f, a6 = 0.f, a7 = 0.f;
    float a8 = 0.f, a9 = 0.f, a10 = 0.f, a11 = 0.f, a12 = 0.f, a13 = 0.f, a14 = 0.f, a15 = 0.f;
#pragma unroll 1
    for (int k = 0; k < 128; ++k) {                // one 16-float W2 slice/iter (s_load)
        float h = fmaxf(fmaf(xa.y, W1[128 + k], fmaf(xa.x, W1[k], b1[k])), 0.f);
        const float* w = &W2[k * 64 + q * 16];     // wave-uniform -> s_load
        a0  = fmaf(h, w[0],  a0);  a1  = fmaf(h, w[1],  a1);
        a2  = fmaf(h, w[2],  a2);  a3  = fmaf(h, w[3],  a3);
        a4  = fmaf(h, w[4],  a4);  a5  = fmaf(h, w[5],  a5);
        a6  = fmaf(h, w[6],  a6);  a7  = fmaf(h, w[7],  a7);
        a8  = fmaf(h, w[8],  a8);  a9  = fmaf(h, w[9],  a9);
        a10 = fmaf(h, w[10], a10); a11 = fmaf(h, w[11], a11);
        a12 = fmaf(h, w[12], a12); a13 = fmaf(h, w[13], a13);
        a14 = fmaf(h, w[14], a14); a15 = fmaf(h, w[15], a15);
        // liveness pin: all 16 accs live in VGPRs through every iteration
        asm volatile("" : "+v"(a0), "+v"(a1), "+v"(a2), "+v"(a3),
                          "+v"(a4), "+v"(a5), "+v"(a6), "+v"(a7),
                          "+v"(a8), "+v"(a9), "+v"(a10), "+v"(a11),
                          "+v"(a12), "+v"(a13), "+v"(a14), "+v"(a15));
    }
    float di = dinv[i];
    union { __half2 h2[8]; int4 q4[2]; } u;
    u.h2[0] = __floats2half2_rn(a0 * di,  a1 * di);
    u.h2[1] = __floats2half2_rn(a2 * di,  a3 * di);
    u.h2[2] = __floats2half2_rn(a4 * di,  a5 * di);
    u.h2[3] = __floats2half2_rn(a6 * di,  a7 * di);
    u.h2[4] = __floats2half2_rn(a8 * di,  a9 * di);
    u.h2[5] = __floats2half2_rn(a10 * di, a11 * di);
    u.h2[6] = __floats2half2_rn(a12 * di, a13 * di);
    u.h2[7] = __floats2half2_rn(a14 * di, a15 * di);
    int4* mo = reinterpret_cast<int4*>(m2h + (size_t)i * 64 + q * 16);
    mo[0] = u.q4[0]; mo[1] = u.q4[1];
}

// ---------------- layer 2 gather + full epilogue ----------------
// fp16 m2 rows = 128B; lane = (edge_slot[0..7], f8[0..7]). Round-10 left this
// latency-bound with 1 row-gather VMEM in flight per wave. Now: 2 NODES per
// wave, both nodes' gathers issued back-to-back before either reduce -> 2x
// outstanding loads, half the waves. deg<=7 still completes in one iteration.
__global__ __launch_bounds__(256) void k_l2out(
    const __half* __restrict__ m2h, const float* __restrict__ dinv,
    const int* __restrict__ row_off, const int* __restrict__ csr_src,
    const float* __restrict__ b2, const float* __restrict__ Wp,
    const float* __restrict__ bp, float* __restrict__ out, int n) {
    int tid = threadIdx.x;
    int wid = tid >> 6, lane = tid & 63;
    int es = lane >> 3;                            // edge slot 0..7
    int f8 = lane & 7;                             // feature octet 0..7
    int iA = (blockIdx.x * 4 + wid) * 2;           // node pair (iA, iA+1)
    if (iA >= n) return;
    int iB = iA + 1;
    bool hasB = iB < n;
    int rA0 = row_off[iA], rA1 = row_off[iA + 1];
    int rB1 = hasB ? row_off[iB + 1] : rA1;
    int cntA = rA1 - rA0 + 1;                      // neighbors + self
    int cntB = hasB ? (rB1 - rA1 + 1) : 0;
    float aA[8], aB[8];
#pragma unroll
    for (int j = 0; j < 8; ++j) { aA[j] = 0.f; aB[j] = 0.f; }
    int cmax = cntA > cntB ? cntA : cntB;
    for (int e = es; e < cmax; e += 8) {
        bool doA = e < cntA, doB = e < cntB;
        int sA = 0, sB = 0;
        if (doA) sA = (e == 0) ? iA : csr_src[rA0 + e - 1];
        if (doB) sB = (e == 0) ? iB : csr_src[rA1 + e - 1];
        int4 vA, vB;                               // both gathers in flight together
        if (doA) vA = *reinterpret_cast<const int4*>(m2h + (size_t)sA * 64 + f8 * 8);
        if (doB) vB = *reinterpret_cast<const int4*>(m2h + (size_t)sB * 64 + f8 * 8);
        if (doA) {
            const __half2* hv = reinterpret_cast<const __half2*>(&vA);
#pragma unroll
            for (int j = 0; j < 4; ++j) {
                float2 f2 = __half22float2(hv[j]);
                aA[2 * j] += f2.x; aA[2 * j + 1] += f2.y;
            }
        }
        if (doB) {
            const __half2* hv = reinterpret_cast<const __half2*>(&vB);
#pragma unroll
            for (int j = 0; j < 4; ++j) {
                float2 f2 = __half22float2(hv[j]);
                aB[2 * j] += f2.x; aB[2 * j + 1] += f2.y;
            }
        }
    }
#pragma unroll
    for (int off = 8; off < 64; off <<= 1) {       // reduce 8 edge slots (bits 3..5)
#pragma unroll
        for (int j = 0; j < 8; ++j) {
            aA[j] += __shfl_xor(aA[j], off);
            aB[j] += __shfl_xor(aB[j], off);
        }
    }
    float4 b2a = reinterpret_cast<const float4*>(b2)[f8 * 2];
    float4 b2b = reinterpret_cast<const float4*>(b2)[f8 * 2 + 1];
    float4 wpa = reinterpret_cast<const float4*>(Wp)[f8 * 2];
    float4 wpb = reinterpret_cast<const float4*>(Wp)[f8 * 2 + 1];
    float diA = dinv[iA];
    float vA = fmaxf(fmaf(aA[0], diA, b2a.x), 0.f) * wpa.x
             + fmaxf(fmaf(aA[1], diA, b2a.y), 0.f) * wpa.y
             + fmaxf(fmaf(aA[2], diA, b2a.z), 0.f) * wpa.z
             + fmaxf(fmaf(aA[3], diA, b2a.w), 0.f) * wpa.w
             + fmaxf(fmaf(aA[4], diA, b2b.x), 0.f) * wpb.x
             + fmaxf(fmaf(aA[5], diA, b2b.y), 0.f) * wpb.y
             + fmaxf(fmaf(aA[6], diA, b2b.z), 0.f) * wpb.z
             + fmaxf(fmaf(aA[7], diA, b2b.w), 0.f) * wpb.w;
    float diB = hasB ? dinv[iB] : 0.f;
    float vB = fmaxf(fmaf(aB[0], diB, b2a.x), 0.f) * wpa.x
             + fmaxf(fmaf(aB[1], diB, b2a.y), 0.f) * wpa.y
             + fmaxf(fmaf(aB[2], diB, b2a.z), 0.f) * wpa.z
             + fmaxf(fmaf(aB[3], diB, b2a.w), 0.f) * wpa.w
             + fmaxf(fmaf(aB[4], diB, b2b.x), 0.f) * wpb.x
             + fmaxf(fmaf(aB[5], diB, b2b.y), 0.f) * wpb.y
             + fmaxf(fmaf(aB[6], diB, b2b.z), 0.f) * wpb.z
             + fmaxf(fmaf(aB[7], diB, b2b.w), 0.f) * wpb.w;
#pragma unroll
    for (int off = 1; off < 8; off <<= 1) {        // reduce the 8 f8 groups
        vA += __shfl_xor(vA, off);
        vB += __shfl_xor(vB, off);
    }
    if (lane == 0) {
        float bp0 = bp[0];
        out[iA] = 1.f / (1.f + expf(-(vA + bp0)));
        if (hasB) out[iB] = 1.f / (1.f + expf(-(vB + bp0)));
    }
}

extern "C" void kernel_launch(void* const* d_in, const int* in_sizes, int n_in,
                              void* d_out, int out_size, void* d_ws, size_t ws_size,
                              hipStream_t stream) {
    const float* x  = (const float*)d_in[0];
    const int*   ei = (const int*)d_in[1];   // [2, E] int32
    const float* W1 = (const float*)d_in[2];
    const float* b1 = (const float*)d_in[3];
    const float* W2 = (const float*)d_in[4];
    const float* b2 = (const float*)d_in[5];
    const float* Wp = (const float*)d_in[6];
    const float* bp = (const float*)d_in[7];
    float* out = (float*)d_out;

    int n = in_sizes[0] / 2;
    int E = in_sizes[1] / 2;
    const int* src = ei;
    const int* dst = ei + E;

    char* ws = (char*)d_ws;
    size_t off = 0;
    auto alloc = [&](size_t bytes) -> void* {
        void* p = ws + off;
        off += (bytes + 255) & ~(size_t)255;
        return p;
    };
    int nb = (n + SCAN_EPB - 1) / SCAN_EPB;
    int*    deg     = (int*)alloc((size_t)n * 4);
    int*    bsum    = (int*)alloc((size_t)nb * 4);
    int*    row_off = (int*)alloc((size_t)(n + 1) * 4);
    int*    cursor  = (int*)alloc((size_t)n * 4);
    float*  dinv    = (float*)alloc((size_t)n * 4);
    float2* xsc     = (float2*)alloc((size_t)n * 8);
    float2* xam     = (float2*)alloc((size_t)n * 8);
    int*    csr_src = (int*)alloc((size_t)E * 4);
    __half* m2h     = (__half*)alloc((size_t)n * 64 * 2);
    (void)ws_size;

    hipMemsetAsync(deg, 0, (size_t)n * 4, stream);
    k_deg      <<<(E + 255) / 256, 256, 0, stream>>>(dst, deg, E);
    k_blocksum <<<nb, SCAN_TPB, 0, stream>>>(deg, bsum, n);
    k_scanbsum <<<1, 256, 0, stream>>>(bsum, row_off, nb, n);
    k_scanfinal<<<nb, SCAN_TPB, 0, stream>>>(deg, bsum, row_off, cursor, n);
    k_dinvx    <<<(n + 255) / 256, 256, 0, stream>>>(deg, x, dinv, xsc, n);
    k_fill     <<<(E + 255) / 256, 256, 0, stream>>>(src, dst, cursor, csr_src, E);
    k_agg1     <<<(n + 255) / 256, 256, 0, stream>>>(xsc, dinv, row_off, csr_src, xam, n);
    dim3 ggrid((n + 255) / 256, 4);
    k_gemm1    <<<ggrid, 256, 0, stream>>>(xam, dinv, W1, b1, W2, m2h, n);
    k_l2out    <<<(n + 7) / 8, 256, 0, stream>>>(m2h, dinv, row_off, csr_src,
                                                 b2, Wp, bp, out, n);
}

// Round 12
// 195.262 us; speedup vs baseline: 1.1352x; 1.1319x over previous
//
#include <hip/hip_runtime.h>
#include <hip/hip_fp16.h>
#include <math.h>

typedef _Float16 f16x8 __attribute__((ext_vector_type(8)));
typedef float f32x4 __attribute__((ext_vector_type(4)));

constexpr int SCAN_TPB = 256;
constexpr int SCAN_EPT = 8;                      // elements per thread
constexpr int SCAN_EPB = SCAN_TPB * SCAN_EPT;    // 2048 per block

// ---------------- degree (in-degree over dst) ----------------
__global__ void k_deg(const int* __restrict__ dst, int* __restrict__ deg, int E) {
    int i = blockIdx.x * blockDim.x + threadIdx.x;
    if (i < E) atomicAdd(&deg[dst[i]], 1);
}

// ---------------- scan phase A: per-block sums ----------------
__global__ __launch_bounds__(SCAN_TPB) void k_blocksum(const int* __restrict__ deg,
                                                       int* __restrict__ bsum, int n) {
    int t = threadIdx.x;
    int idx0 = blockIdx.x * SCAN_EPB + t * SCAN_EPT;
    int s = 0;
    if (idx0 + SCAN_EPT <= n) {
        const int4* p = reinterpret_cast<const int4*>(deg + idx0);
        int4 a = p[0], b = p[1];
        s = a.x + a.y + a.z + a.w + b.x + b.y + b.z + b.w;
    } else {
        for (int k = 0; k < SCAN_EPT; ++k) { int i = idx0 + k; if (i < n) s += deg[i]; }
    }
#pragma unroll
    for (int off = 32; off; off >>= 1) s += __shfl_xor(s, off);
    __shared__ int wsum[4];
    int lane = t & 63, wid = t >> 6;
    if (lane == 0) wsum[wid] = s;
    __syncthreads();
    if (t == 0) bsum[blockIdx.x] = wsum[0] + wsum[1] + wsum[2] + wsum[3];
}

// ---------------- scan phase B: exclusive-scan the block sums (tiny) ----------------
__global__ __launch_bounds__(256) void k_scanbsum(int* __restrict__ bsum,
                                                  int* __restrict__ row_off, int nb, int n) {
    int t = threadIdx.x, lane = t & 63, wid = t >> 6;
    __shared__ int wsum[4];
    int carry = 0;
    for (int base = 0; base < nb; base += 256) {
        int i = base + t;
        int v = (i < nb) ? bsum[i] : 0;
        int s = v;
#pragma unroll
        for (int off = 1; off < 64; off <<= 1) { int u = __shfl_up(s, off); if (lane >= off) s += u; }
        if (lane == 63) wsum[wid] = s;
        __syncthreads();
        int add = carry;
        for (int w = 0; w < wid; ++w) add += wsum[w];
        if (i < nb) bsum[i] = s - v + add;        // exclusive + carry
        carry += wsum[0] + wsum[1] + wsum[2] + wsum[3];
        __syncthreads();
    }
    if (t == 0) row_off[n] = carry;               // total edge count
}

// ---------------- scan phase C: final scan, write row_off + cursor ----------------
__global__ __launch_bounds__(SCAN_TPB) void k_scanfinal(const int* __restrict__ deg,
                                                        const int* __restrict__ bsum,
                                                        int* __restrict__ row_off,
                                                        int* __restrict__ cursor, int n) {
    int t = threadIdx.x, lane = t & 63, wid = t >> 6;
    int idx0 = blockIdx.x * SCAN_EPB + t * SCAN_EPT;
    int e[SCAN_EPT];
    bool full = (idx0 + SCAN_EPT <= n);
    if (full) {
        const int4* p = reinterpret_cast<const int4*>(deg + idx0);
        int4 a = p[0], b = p[1];
        e[0] = a.x; e[1] = a.y; e[2] = a.z; e[3] = a.w;
        e[4] = b.x; e[5] = b.y; e[6] = b.z; e[7] = b.w;
    } else {
        for (int k = 0; k < SCAN_EPT; ++k) { int i = idx0 + k; e[k] = (i < n) ? deg[i] : 0; }
    }
    int tsum = 0;
#pragma unroll
    for (int k = 0; k < SCAN_EPT; ++k) tsum += e[k];
    int s = tsum;
#pragma unroll
    for (int off = 1; off < 64; off <<= 1) { int u = __shfl_up(s, off); if (lane >= off) s += u; }
    __shared__ int wsum[4];
    if (lane == 63) wsum[wid] = s;
    __syncthreads();
    int add = bsum[blockIdx.x];
    for (int w = 0; w < wid; ++w) add += wsum[w];
    int run = s - tsum + add;                     // thread's exclusive prefix
    int o[SCAN_EPT];
#pragma unroll
    for (int k = 0; k < SCAN_EPT; ++k) { o[k] = run; run += e[k]; }
    if (full) {
        int4* ro = reinterpret_cast<int4*>(row_off + idx0);
        int4* cu = reinterpret_cast<int4*>(cursor + idx0);
        ro[0] = make_int4(o[0], o[1], o[2], o[3]);
        ro[1] = make_int4(o[4], o[5], o[6], o[7]);
        cu[0] = make_int4(o[0], o[1], o[2], o[3]);
        cu[1] = make_int4(o[4], o[5], o[6], o[7]);
    } else {
        for (int k = 0; k < SCAN_EPT; ++k) {
            int i = idx0 + k;
            if (i < n) { row_off[i] = o[k]; cursor[i] = o[k]; }
        }
    }
}

// ---------------- dinv + pre-scaled features xsc[i] = x[i]*dinv[i] ----------------
__global__ void k_dinvx(const int* __restrict__ deg, const float* __restrict__ x,
                        float* __restrict__ dinv, float2* __restrict__ xsc, int n) {
    int i = blockIdx.x * blockDim.x + threadIdx.x;
    if (i < n) {
        float di = rsqrtf((float)deg[i] + 1.0f);  // +1 self loop, always > 0
        dinv[i] = di;
        xsc[i] = make_float2(x[2 * i] * di, x[2 * i + 1] * di);
    }
}

// ---------------- CSR fill (counting sort by dst) ----------------
__global__ void k_fill(const int* __restrict__ src, const int* __restrict__ dst,
                       int* __restrict__ cursor, int* __restrict__ csr_src, int E) {
    int e = blockIdx.x * blockDim.x + threadIdx.x;
    if (e < E) {
        int pos = atomicAdd(&cursor[dst[e]], 1);
        csr_src[pos] = src[e];
    }
}

// ---------------- layer-1 sparse aggregation: xam[i] = dinv[i]*(xsc[i] + sum_nbr xsc[s])
__global__ __launch_bounds__(256) void k_agg1(
    const float2* __restrict__ xsc, const float* __restrict__ dinv,
    const int* __restrict__ row_off, const int* __restrict__ csr_src,
    float2* __restrict__ xam, int n) {
    int i = blockIdx.x * blockDim.x + threadIdx.x;
    if (i >= n) return;
    int r0 = row_off[i], r1 = row_off[i + 1];
    float2 self = xsc[i];
    float xa0 = self.x, xa1 = self.y;
    for (int j = r0; j < r1; ++j) {
        float2 v = xsc[csr_src[j]];               // 8B gather, xsc=1.6MB L2-resident
        xa0 += v.x; xa1 += v.y;
    }
    float di = dinv[i];
    xam[i] = make_float2(xa0 * di, xa1 * di);
}

// ---------------- W2 -> fp16 transposed [64][128] (B-frag b128 loads) ----------------
__global__ void k_prepw(const float* __restrict__ W2, __half* __restrict__ w2t) {
    int idx = blockIdx.x * 256 + threadIdx.x;
    if (idx < 128 * 64) {
        int k = idx >> 6, f = idx & 63;
        w2t[f * 128 + k] = __float2half(W2[idx]);
    }
}

// ---------------- h1 = relu(xam@W1 + b1), fp16 [N][128] ----------------
// 16 nodes x 16 k-chunks of 8 per block; consecutive tids write consecutive
// 16B -> fully coalesced. Write-once pattern: nothing for regalloc to mangle.
__global__ __launch_bounds__(256) void k_h1(
    const float2* __restrict__ xam, const float* __restrict__ W1,
    const float* __restrict__ b1, __half* __restrict__ h1h, int n) {
    int tid = threadIdx.x;
    int nl = tid >> 4, ch = tid & 15;
    int i = blockIdx.x * 16 + nl;
    if (i >= n) return;
    float2 xa = xam[i];
    int k0 = ch * 8;
    float4 wa0 = *reinterpret_cast<const float4*>(&W1[k0]);
    float4 wa1 = *reinterpret_cast<const float4*>(&W1[k0 + 4]);
    float4 wb0 = *reinterpret_cast<const float4*>(&W1[128 + k0]);
    float4 wb1 = *reinterpret_cast<const float4*>(&W1[128 + k0 + 4]);
    float4 bb0 = *reinterpret_cast<const float4*>(&b1[k0]);
    float4 bb1 = *reinterpret_cast<const float4*>(&b1[k0 + 4]);
    float h0 = fmaxf(fmaf(xa.y, wb0.x, fmaf(xa.x, wa0.x, bb0.x)), 0.f);
    float h1 = fmaxf(fmaf(xa.y, wb0.y, fmaf(xa.x, wa0.y, bb0.y)), 0.f);
    float h2 = fmaxf(fmaf(xa.y, wb0.z, fmaf(xa.x, wa0.z, bb0.z)), 0.f);
    float h3 = fmaxf(fmaf(xa.y, wb0.w, fmaf(xa.x, wa0.w, bb0.w)), 0.f);
    float h4 = fmaxf(fmaf(xa.y, wb1.x, fmaf(xa.x, wa1.x, bb1.x)), 0.f);
    float h5 = fmaxf(fmaf(xa.y, wb1.y, fmaf(xa.x, wa1.y, bb1.y)), 0.f);
    float h6 = fmaxf(fmaf(xa.y, wb1.z, fmaf(xa.x, wa1.z, bb1.z)), 0.f);
    float h7 = fmaxf(fmaf(xa.y, wb1.w, fmaf(xa.x, wa1.w, bb1.w)), 0.f);
    union { __half2 h2v[4]; int4 q; } u;
    u.h2v[0] = __floats2half2_rn(h0, h1);
    u.h2v[1] = __floats2half2_rn(h2, h3);
    u.h2v[2] = __floats2half2_rn(h4, h5);
    u.h2v[3] = __floats2half2_rn(h6, h7);
    *reinterpret_cast<int4*>(h1h + (size_t)i * 128 + k0) = u.q;
}

// ---------------- layer-1 GEMM on MFMA: m2 = (h1 @ W2) * dinv, fp16 out ----------
// Rounds 8-11 lesson: the fp32 VALU formulation floors at ~80 µs (compiler
// strip-mines accumulators; pin costs movs). This is matmul-shaped, K=128 ->
// matrix cores. Wave = 16 nodes x 64 feats: A-frag = b128 from h1h (lane&15 =
// row, lane>>4 = k-octet), B-frags hoisted (16 x b128 from w2t), 16x
// mfma_f32_16x16x32_f16, C/D per verified mapping (col=lane&15,
// row=(lane>>4)*4+reg). Epilogue: LDS bounce -> dinv scale -> coalesced fp16.
__global__ __launch_bounds__(256, 2) void k_gemm1m(
    const __half* __restrict__ h1h, const __half* __restrict__ w2t,
    const float* __restrict__ dinv, __half* __restrict__ m2h, int n) {
    __shared__ __align__(16) float cs[4][16][68];
    int tid = threadIdx.x;
    int w = tid >> 6, lane = tid & 63;
    int col = lane & 15, kg = lane >> 4;
    int base = (blockIdx.x * 4 + w) * 16;          // 16 nodes per wave

    f16x8 bf[4][4];                                // B frags [f-tile][k-step]
#pragma unroll
    for (int ft = 0; ft < 4; ++ft)
#pragma unroll
        for (int t = 0; t < 4; ++t)
            bf[ft][t] = *reinterpret_cast<const f16x8*>(
                w2t + (ft * 16 + col) * 128 + t * 32 + kg * 8);

    int an = base + col; if (an >= n) an = 0;      // A row (clamped; store guarded)
    f32x4 c0 = {}, c1 = {}, c2 = {}, c3 = {};
#pragma unroll
    for (int t = 0; t < 4; ++t) {
        f16x8 a = *reinterpret_cast<const f16x8*>(
            h1h + (size_t)an * 128 + t * 32 + kg * 8);
        c0 = __builtin_amdgcn_mfma_f32_16x16x32_f16(a, bf[0][t], c0, 0, 0, 0);
        c1 = __builtin_amdgcn_mfma_f32_16x16x32_f16(a, bf[1][t], c1, 0, 0, 0);
        c2 = __builtin_amdgcn_mfma_f32_16x16x32_f16(a, bf[2][t], c2, 0, 0, 0);
        c3 = __builtin_amdgcn_mfma_f32_16x16x32_f16(a, bf[3][t], c3, 0, 0, 0);
    }
#pragma unroll
    for (int r = 0; r < 4; ++r) {                  // C row = kg*4+r, col = ft*16+col
        cs[w][kg * 4 + r][0 * 16 + col] = c0[r];
        cs[w][kg * 4 + r][1 * 16 + col] = c1[r];
        cs[w][kg * 4 + r][2 * 16 + col] = c2[r];
        cs[w][kg * 4 + r][3 * 16 + col] = c3[r];
    }
    __syncthreads();
    int nl = tid >> 2, ch = tid & 3;               // node-in-block, 16-feature chunk
    int node = blockIdx.x * 64 + nl;
    if (node < n) {
        float di = dinv[node];
        const float* row = &cs[nl >> 4][nl & 15][ch * 16];
        union { __half2 h2v[8]; int4 q[2]; } u;
#pragma unroll
        for (int j = 0; j < 8; ++j)
            u.h2v[j] = __floats2half2_rn(row[2 * j] * di, row[2 * j + 1] * di);
        int4* dst = reinterpret_cast<int4*>(m2h + (size_t)node * 64 + ch * 16);
        dst[0] = u.q[0]; dst[1] = u.q[1];
    }
}

// ---------------- layer 2 gather + full epilogue ----------------
// fp16 m2 rows = 128B; lane = (edge_slot[0..7], f8[0..7]); 2 nodes per wave
// with both nodes' gathers issued back-to-back (2x VMEM in flight).
__global__ __launch_bounds__(256) void k_l2out(
    const __half* __restrict__ m2h, const float* __restrict__ dinv,
    const int* __restrict__ row_off, const int* __restrict__ csr_src,
    const float* __restrict__ b2, const float* __restrict__ Wp,
    const float* __restrict__ bp, float* __restrict__ out, int n) {
    int tid = threadIdx.x;
    int wid = tid >> 6, lane = tid & 63;
    int es = lane >> 3;                            // edge slot 0..7
    int f8 = lane & 7;                             // feature octet 0..7
    int iA = (blockIdx.x * 4 + wid) * 2;           // node pair (iA, iA+1)
    if (iA >= n) return;
    int iB = iA + 1;
    bool hasB = iB < n;
    int rA0 = row_off[iA], rA1 = row_off[iA + 1];
    int rB1 = hasB ? row_off[iB + 1] : rA1;
    int cntA = rA1 - rA0 + 1;                      // neighbors + self
    int cntB = hasB ? (rB1 - rA1 + 1) : 0;
    float aA[8], aB[8];
#pragma unroll
    for (int j = 0; j < 8; ++j) { aA[j] = 0.f; aB[j] = 0.f; }
    int cmax = cntA > cntB ? cntA : cntB;
    for (int e = es; e < cmax; e += 8) {
        bool doA = e < cntA, doB = e < cntB;
        int sA = 0, sB = 0;
        if (doA) sA = (e == 0) ? iA : csr_src[rA0 + e - 1];
        if (doB) sB = (e == 0) ? iB : csr_src[rA1 + e - 1];
        int4 vA, vB;                               // both gathers in flight together
        if (doA) vA = *reinterpret_cast<const int4*>(m2h + (size_t)sA * 64 + f8 * 8);
        if (doB) vB = *reinterpret_cast<const int4*>(m2h + (size_t)sB * 64 + f8 * 8);
        if (doA) {
            const __half2* hv = reinterpret_cast<const __half2*>(&vA);
#pragma unroll
            for (int j = 0; j < 4; ++j) {
                float2 f2 = __half22float2(hv[j]);
                aA[2 * j] += f2.x; aA[2 * j + 1] += f2.y;
            }
        }
        if (doB) {
            const __half2* hv = reinterpret_cast<const __half2*>(&vB);
#pragma unroll
            for (int j = 0; j < 4; ++j) {
                float2 f2 = __half22float2(hv[j]);
                aB[2 * j] += f2.x; aB[2 * j + 1] += f2.y;
            }
        }
    }
#pragma unroll
    for (int off = 8; off < 64; off <<= 1) {       // reduce 8 edge slots (bits 3..5)
#pragma unroll
        for (int j = 0; j < 8; ++j) {
            aA[j] += __shfl_xor(aA[j], off);
            aB[j] += __shfl_xor(aB[j], off);
        }
    }
    float4 b2a = reinterpret_cast<const float4*>(b2)[f8 * 2];
    float4 b2b = reinterpret_cast<const float4*>(b2)[f8 * 2 + 1];
    float4 wpa = reinterpret_cast<const float4*>(Wp)[f8 * 2];
    float4 wpb = reinterpret_cast<const float4*>(Wp)[f8 * 2 + 1];
    float diA = dinv[iA];
    float vA = fmaxf(fmaf(aA[0], diA, b2a.x), 0.f) * wpa.x
             + fmaxf(fmaf(aA[1], diA, b2a.y), 0.f) * wpa.y
             + fmaxf(fmaf(aA[2], diA, b2a.z), 0.f) * wpa.z
             + fmaxf(fmaf(aA[3], diA, b2a.w), 0.f) * wpa.w
             + fmaxf(fmaf(aA[4], diA, b2b.x), 0.f) * wpb.x
             + fmaxf(fmaf(aA[5], diA, b2b.y), 0.f) * wpb.y
             + fmaxf(fmaf(aA[6], diA, b2b.z), 0.f) * wpb.z
             + fmaxf(fmaf(aA[7], diA, b2b.w), 0.f) * wpb.w;
    float diB = hasB ? dinv[iB] : 0.f;
    float vB = fmaxf(fmaf(aB[0], diB, b2a.x), 0.f) * wpa.x
             + fmaxf(fmaf(aB[1], diB, b2a.y), 0.f) * wpa.y
             + fmaxf(fmaf(aB[2], diB, b2a.z), 0.f) * wpa.z
             + fmaxf(fmaf(aB[3], diB, b2a.w), 0.f) * wpa.w
             + fmaxf(fmaf(aB[4], diB, b2b.x), 0.f) * wpb.x
             + fmaxf(fmaf(aB[5], diB, b2b.y), 0.f) * wpb.y
             + fmaxf(fmaf(aB[6], diB, b2b.z), 0.f) * wpb.z
             + fmaxf(fmaf(aB[7], diB, b2b.w), 0.f) * wpb.w;
#pragma unroll
    for (int off = 1; off < 8; off <<= 1) {        // reduce the 8 f8 groups
        vA += __shfl_xor(vA, off);
        vB += __shfl_xor(vB, off);
    }
    if (lane == 0) {
        float bp0 = bp[0];
        out[iA] = 1.f / (1.f + expf(-(vA + bp0)));
        if (hasB) out[iB] = 1.f / (1.f + expf(-(vB + bp0)));
    }
}

extern "C" void kernel_launch(void* const* d_in, const int* in_sizes, int n_in,
                              void* d_out, int out_size, void* d_ws, size_t ws_size,
                              hipStream_t stream) {
    const float* x  = (const float*)d_in[0];
    const int*   ei = (const int*)d_in[1];   // [2, E] int32
    const float* W1 = (const float*)d_in[2];
    const float* b1 = (const float*)d_in[3];
    const float* W2 = (const float*)d_in[4];
    const float* b2 = (const float*)d_in[5];
    const float* Wp = (const float*)d_in[6];
    const float* bp = (const float*)d_in[7];
    float* out = (float*)d_out;

    int n = in_sizes[0] / 2;
    int E = in_sizes[1] / 2;
    const int* src = ei;
    const int* dst = ei + E;

    char* ws = (char*)d_ws;
    size_t off = 0;
    auto alloc = [&](size_t bytes) -> void* {
        void* p = ws + off;
        off += (bytes + 255) & ~(size_t)255;
        return p;
    };
    int nb = (n + SCAN_EPB - 1) / SCAN_EPB;
    int*    deg     = (int*)alloc((size_t)n * 4);
    int*    bsum    = (int*)alloc((size_t)nb * 4);
    int*    row_off = (int*)alloc((size_t)(n + 1) * 4);
    int*    cursor  = (int*)alloc((size_t)n * 4);
    float*  dinv    = (float*)alloc((size_t)n * 4);
    float2* xsc     = (float2*)alloc((size_t)n * 8);
    float2* xam     = (float2*)alloc((size_t)n * 8);
    int*    csr_src = (int*)alloc((size_t)E * 4);
    __half* w2t     = (__half*)alloc((size_t)128 * 64 * 2);
    __half* h1h     = (__half*)alloc((size_t)n * 128 * 2);
    __half* m2h     = (__half*)alloc((size_t)n * 64 * 2);
    (void)ws_size;

    hipMemsetAsync(deg, 0, (size_t)n * 4, stream);
    k_prepw    <<<32, 256, 0, stream>>>(W2, w2t);
    k_deg      <<<(E + 255) / 256, 256, 0, stream>>>(dst, deg, E);
    k_blocksum <<<nb, SCAN_TPB, 0, stream>>>(deg, bsum, n);
    k_scanbsum <<<1, 256, 0, stream>>>(bsum, row_off, nb, n);
    k_scanfinal<<<nb, SCAN_TPB, 0, stream>>>(deg, bsum, row_off, cursor, n);
    k_dinvx    <<<(n + 255) / 256, 256, 0, stream>>>(deg, x, dinv, xsc, n);
    k_fill     <<<(E + 255) / 256, 256, 0, stream>>>(src, dst, cursor, csr_src, E);
    k_agg1     <<<(n + 255) / 256, 256, 0, stream>>>(xsc, dinv, row_off, csr_src, xam, n);
    k_h1       <<<(n + 15) / 16, 256, 0, stream>>>(xam, W1, b1, h1h, n);
    k_gemm1m   <<<(n + 63) / 64, 256, 0, stream>>>(h1h, w2t, dinv, m2h, n);
    k_l2out    <<<(n + 7) / 8, 256, 0, stream>>>(m2h, dinv, row_off, csr_src,
                                                 b2, Wp, bp, out, n);
}

// Round 13
// 159.876 us; speedup vs baseline: 1.3864x; 1.2213x over previous
//
#include <hip/hip_runtime.h>
#include <hip/hip_fp16.h>
#include <math.h>

typedef _Float16 f16x8 __attribute__((ext_vector_type(8)));
typedef float f32x4 __attribute__((ext_vector_type(4)));

constexpr int SCAN_TPB = 256;
constexpr int SCAN_EPT = 8;                      // elements per thread
constexpr int SCAN_EPB = SCAN_TPB * SCAN_EPT;    // 2048 per block

// ---------------- degree (in-degree over dst) ----------------
__global__ void k_deg(const int* __restrict__ dst, int* __restrict__ deg, int E) {
    int i = blockIdx.x * blockDim.x + threadIdx.x;
    if (i < E) atomicAdd(&deg[dst[i]], 1);
}

// ---------------- scan phase A: per-block sums ----------------
__global__ __launch_bounds__(SCAN_TPB) void k_blocksum(const int* __restrict__ deg,
                                                       int* __restrict__ bsum, int n) {
    int t = threadIdx.x;
    int idx0 = blockIdx.x * SCAN_EPB + t * SCAN_EPT;
    int s = 0;
    if (idx0 + SCAN_EPT <= n) {
        const int4* p = reinterpret_cast<const int4*>(deg + idx0);
        int4 a = p[0], b = p[1];
        s = a.x + a.y + a.z + a.w + b.x + b.y + b.z + b.w;
    } else {
        for (int k = 0; k < SCAN_EPT; ++k) { int i = idx0 + k; if (i < n) s += deg[i]; }
    }
#pragma unroll
    for (int off = 32; off; off >>= 1) s += __shfl_xor(s, off);
    __shared__ int wsum[4];
    int lane = t & 63, wid = t >> 6;
    if (lane == 0) wsum[wid] = s;
    __syncthreads();
    if (t == 0) bsum[blockIdx.x] = wsum[0] + wsum[1] + wsum[2] + wsum[3];
}

// ---------------- scan phase B: exclusive-scan the block sums (tiny) ----------------
__global__ __launch_bounds__(256) void k_scanbsum(int* __restrict__ bsum,
                                                  int* __restrict__ row_off, int nb, int n) {
    int t = threadIdx.x, lane = t & 63, wid = t >> 6;
    __shared__ int wsum[4];
    int carry = 0;
    for (int base = 0; base < nb; base += 256) {
        int i = base + t;
        int v = (i < nb) ? bsum[i] : 0;
        int s = v;
#pragma unroll
        for (int off = 1; off < 64; off <<= 1) { int u = __shfl_up(s, off); if (lane >= off) s += u; }
        if (lane == 63) wsum[wid] = s;
        __syncthreads();
        int add = carry;
        for (int w = 0; w < wid; ++w) add += wsum[w];
        if (i < nb) bsum[i] = s - v + add;        // exclusive + carry
        carry += wsum[0] + wsum[1] + wsum[2] + wsum[3];
        __syncthreads();
    }
    if (t == 0) row_off[n] = carry;               // total edge count
}

// ---------------- scan phase C: final scan, write row_off + cursor ----------------
__global__ __launch_bounds__(SCAN_TPB) void k_scanfinal(const int* __restrict__ deg,
                                                        const int* __restrict__ bsum,
                                                        int* __restrict__ row_off,
                                                        int* __restrict__ cursor, int n) {
    int t = threadIdx.x, lane = t & 63, wid = t >> 6;
    int idx0 = blockIdx.x * SCAN_EPB + t * SCAN_EPT;
    int e[SCAN_EPT];
    bool full = (idx0 + SCAN_EPT <= n);
    if (full) {
        const int4* p = reinterpret_cast<const int4*>(deg + idx0);
        int4 a = p[0], b = p[1];
        e[0] = a.x; e[1] = a.y; e[2] = a.z; e[3] = a.w;
        e[4] = b.x; e[5] = b.y; e[6] = b.z; e[7] = b.w;
    } else {
        for (int k = 0; k < SCAN_EPT; ++k) { int i = idx0 + k; e[k] = (i < n) ? deg[i] : 0; }
    }
    int tsum = 0;
#pragma unroll
    for (int k = 0; k < SCAN_EPT; ++k) tsum += e[k];
    int s = tsum;
#pragma unroll
    for (int off = 1; off < 64; off <<= 1) { int u = __shfl_up(s, off); if (lane >= off) s += u; }
    __shared__ int wsum[4];
    if (lane == 63) wsum[wid] = s;
    __syncthreads();
    int add = bsum[blockIdx.x];
    for (int w = 0; w < wid; ++w) add += wsum[w];
    int run = s - tsum + add;                     // thread's exclusive prefix
    int o[SCAN_EPT];
#pragma unroll
    for (int k = 0; k < SCAN_EPT; ++k) { o[k] = run; run += e[k]; }
    if (full) {
        int4* ro = reinterpret_cast<int4*>(row_off + idx0);
        int4* cu = reinterpret_cast<int4*>(cursor + idx0);
        ro[0] = make_int4(o[0], o[1], o[2], o[3]);
        ro[1] = make_int4(o[4], o[5], o[6], o[7]);
        cu[0] = make_int4(o[0], o[1], o[2], o[3]);
        cu[1] = make_int4(o[4], o[5], o[6], o[7]);
    } else {
        for (int k = 0; k < SCAN_EPT; ++k) {
            int i = idx0 + k;
            if (i < n) { row_off[i] = o[k]; cursor[i] = o[k]; }
        }
    }
}

// ---------------- dinv + pre-scaled features xsc[i] = x[i]*dinv[i] ----------------
__global__ void k_dinvx(const int* __restrict__ deg, const float* __restrict__ x,
                        float* __restrict__ dinv, float2* __restrict__ xsc, int n) {
    int i = blockIdx.x * blockDim.x + threadIdx.x;
    if (i < n) {
        float di = rsqrtf((float)deg[i] + 1.0f);  // +1 self loop, always > 0
        dinv[i] = di;
        xsc[i] = make_float2(x[2 * i] * di, x[2 * i + 1] * di);
    }
}

// ---------------- CSR fill (counting sort by dst) ----------------
__global__ void k_fill(const int* __restrict__ src, const int* __restrict__ dst,
                       int* __restrict__ cursor, int* __restrict__ csr_src, int E) {
    int e = blockIdx.x * blockDim.x + threadIdx.x;
    if (e < E) {
        int pos = atomicAdd(&cursor[dst[e]], 1);
        csr_src[pos] = src[e];
    }
}

// ---------------- layer-1 sparse aggregation: xam[i] = dinv[i]*(xsc[i] + sum_nbr xsc[s])
__global__ __launch_bounds__(256) void k_agg1(
    const float2* __restrict__ xsc, const float* __restrict__ dinv,
    const int* __restrict__ row_off, const int* __restrict__ csr_src,
    float2* __restrict__ xam, int n) {
    int i = blockIdx.x * blockDim.x + threadIdx.x;
    if (i >= n) return;
    int r0 = row_off[i], r1 = row_off[i + 1];
    float2 self = xsc[i];
    float xa0 = self.x, xa1 = self.y;
    for (int j = r0; j < r1; ++j) {
        float2 v = xsc[csr_src[j]];               // 8B gather, xsc=1.6MB L2-resident
        xa0 += v.x; xa1 += v.y;
    }
    float di = dinv[i];
    xam[i] = make_float2(xa0 * di, xa1 * di);
}

// ---------------- W2 -> fp16 transposed [64][128] (B-frag b128 loads) ----------------
__global__ void k_prepw(const float* __restrict__ W2, __half* __restrict__ w2t) {
    int idx = blockIdx.x * 256 + threadIdx.x;
    if (idx < 128 * 64) {
        int k = idx >> 6, f = idx & 63;
        w2t[f * 128 + k] = __float2half(W2[idx]);
    }
}

// ---------------- h1 = relu(xam@W1 + b1), fp16 [N][128] ----------------
__global__ __launch_bounds__(256) void k_h1(
    const float2* __restrict__ xam, const float* __restrict__ W1,
    const float* __restrict__ b1, __half* __restrict__ h1h, int n) {
    int tid = threadIdx.x;
    int nl = tid >> 4, ch = tid & 15;
    int i = blockIdx.x * 16 + nl;
    if (i >= n) return;
    float2 xa = xam[i];
    int k0 = ch * 8;
    float4 wa0 = *reinterpret_cast<const float4*>(&W1[k0]);
    float4 wa1 = *reinterpret_cast<const float4*>(&W1[k0 + 4]);
    float4 wb0 = *reinterpret_cast<const float4*>(&W1[128 + k0]);
    float4 wb1 = *reinterpret_cast<const float4*>(&W1[128 + k0 + 4]);
    float4 bb0 = *reinterpret_cast<const float4*>(&b1[k0]);
    float4 bb1 = *reinterpret_cast<const float4*>(&b1[k0 + 4]);
    float h0 = fmaxf(fmaf(xa.y, wb0.x, fmaf(xa.x, wa0.x, bb0.x)), 0.f);
    float h1 = fmaxf(fmaf(xa.y, wb0.y, fmaf(xa.x, wa0.y, bb0.y)), 0.f);
    float h2 = fmaxf(fmaf(xa.y, wb0.z, fmaf(xa.x, wa0.z, bb0.z)), 0.f);
    float h3 = fmaxf(fmaf(xa.y, wb0.w, fmaf(xa.x, wa0.w, bb0.w)), 0.f);
    float h4 = fmaxf(fmaf(xa.y, wb1.x, fmaf(xa.x, wa1.x, bb1.x)), 0.f);
    float h5 = fmaxf(fmaf(xa.y, wb1.y, fmaf(xa.x, wa1.y, bb1.y)), 0.f);
    float h6 = fmaxf(fmaf(xa.y, wb1.z, fmaf(xa.x, wa1.z, bb1.z)), 0.f);
    float h7 = fmaxf(fmaf(xa.y, wb1.w, fmaf(xa.x, wa1.w, bb1.w)), 0.f);
    union { __half2 h2v[4]; int4 q; } u;
    u.h2v[0] = __floats2half2_rn(h0, h1);
    u.h2v[1] = __floats2half2_rn(h2, h3);
    u.h2v[2] = __floats2half2_rn(h4, h5);
    u.h2v[3] = __floats2half2_rn(h6, h7);
    *reinterpret_cast<int4*>(h1h + (size_t)i * 128 + k0) = u.q;
}

// ---------------- layer-1 GEMM on MFMA: m2 = (h1 @ W2) * dinv, fp16 out ----------
__global__ __launch_bounds__(256, 2) void k_gemm1m(
    const __half* __restrict__ h1h, const __half* __restrict__ w2t,
    const float* __restrict__ dinv, __half* __restrict__ m2h, int n) {
    __shared__ __align__(16) float cs[4][16][68];
    int tid = threadIdx.x;
    int w = tid >> 6, lane = tid & 63;
    int col = lane & 15, kg = lane >> 4;
    int base = (blockIdx.x * 4 + w) * 16;          // 16 nodes per wave

    f16x8 bf[4][4];                                // B frags [f-tile][k-step]
#pragma unroll
    for (int ft = 0; ft < 4; ++ft)
#pragma unroll
        for (int t = 0; t < 4; ++t)
            bf[ft][t] = *reinterpret_cast<const f16x8*>(
                w2t + (ft * 16 + col) * 128 + t * 32 + kg * 8);

    int an = base + col; if (an >= n) an = 0;      // A row (clamped; store guarded)
    f32x4 c0 = {}, c1 = {}, c2 = {}, c3 = {};
#pragma unroll
    for (int t = 0; t < 4; ++t) {
        f16x8 a = *reinterpret_cast<const f16x8*>(
            h1h + (size_t)an * 128 + t * 32 + kg * 8);
        c0 = __builtin_amdgcn_mfma_f32_16x16x32_f16(a, bf[0][t], c0, 0, 0, 0);
        c1 = __builtin_amdgcn_mfma_f32_16x16x32_f16(a, bf[1][t], c1, 0, 0, 0);
        c2 = __builtin_amdgcn_mfma_f32_16x16x32_f16(a, bf[2][t], c2, 0, 0, 0);
        c3 = __builtin_amdgcn_mfma_f32_16x16x32_f16(a, bf[3][t], c3, 0, 0, 0);
    }
#pragma unroll
    for (int r = 0; r < 4; ++r) {                  // C row = kg*4+r, col = ft*16+col
        cs[w][kg * 4 + r][0 * 16 + col] = c0[r];
        cs[w][kg * 4 + r][1 * 16 + col] = c1[r];
        cs[w][kg * 4 + r][2 * 16 + col] = c2[r];
        cs[w][kg * 4 + r][3 * 16 + col] = c3[r];
    }
    __syncthreads();
    int nl = tid >> 2, ch = tid & 3;               // node-in-block, 16-feature chunk
    int node = blockIdx.x * 64 + nl;
    if (node < n) {
        float di = dinv[node];
        const float* row = &cs[nl >> 4][nl & 15][ch * 16];
        union { __half2 h2v[8]; int4 q[2]; } u;
#pragma unroll
        for (int j = 0; j < 8; ++j)
            u.h2v[j] = __floats2half2_rn(row[2 * j] * di, row[2 * j + 1] * di);
        int4* dst = reinterpret_cast<int4*>(m2h + (size_t)node * 64 + ch * 16);
        dst[0] = u.q[0]; dst[1] = u.q[1];
    }
}

// ---------------- layer 2 gather + full epilogue ----------------
// Round-12 lesson: the slot-parallel shape was ISSUE-bound (VALUBusy 68%):
// 16 VALU per 16B loaded (cvt+add) + 51 shuffles/node-pair. New shape:
// 8 nodes/wave, 8-lane group per node (g=lane>>3, f8=lane&7). Each group walks
// its edge list serially -- 8 independent chains/wave hide gather latency; a
// wave load still covers 8x128B rows. Accumulate in PACKED fp16 (4 pk_add per
// 16B, zero per-edge cvt); convert once at the end; only a 3-shuffle group
// reduce remains (was 51).
__global__ __launch_bounds__(256) void k_l2out(
    const __half* __restrict__ m2h, const float* __restrict__ dinv,
    const int* __restrict__ row_off, const int* __restrict__ csr_src,
    const float* __restrict__ b2, const float* __restrict__ Wp,
    const float* __restrict__ bp, float* __restrict__ out, int n) {
    int tid = threadIdx.x;
    int wid = tid >> 6, lane = tid & 63;
    int g = lane >> 3;                             // node sub-slot 0..7
    int f8 = lane & 7;                             // feature octet 0..7
    int i = (blockIdx.x * 4 + wid) * 8 + g;
    bool valid = i < n;
    int ic = valid ? i : 0;
    int r0 = row_off[ic];
    int r1 = valid ? row_off[ic + 1] : r0;
    // self row initializes the accumulator (the +self term, exact)
    int4 sv = *reinterpret_cast<const int4*>(m2h + (size_t)ic * 64 + f8 * 8);
    const __half2* sh = reinterpret_cast<const __half2*>(&sv);
    __half2 a0 = sh[0], a1 = sh[1], a2 = sh[2], a3 = sh[3];
    for (int j = r0; j < r1; ++j) {                // serial per group; 8 chains/wave
        int s = csr_src[j];                        // uniform in group -> broadcast
        int4 v = *reinterpret_cast<const int4*>(m2h + (size_t)s * 64 + f8 * 8);
        const __half2* hv = reinterpret_cast<const __half2*>(&v);
        a0 = __hadd2(a0, hv[0]); a1 = __hadd2(a1, hv[1]);
        a2 = __hadd2(a2, hv[2]); a3 = __hadd2(a3, hv[3]);
    }
    float2 f0 = __half22float2(a0), f1 = __half22float2(a1);
    float2 f2 = __half22float2(a2), f3 = __half22float2(a3);
    float di = dinv[ic];
    float4 b2a = reinterpret_cast<const float4*>(b2)[f8 * 2];
    float4 b2b = reinterpret_cast<const float4*>(b2)[f8 * 2 + 1];
    float4 wpa = reinterpret_cast<const float4*>(Wp)[f8 * 2];
    float4 wpb = reinterpret_cast<const float4*>(Wp)[f8 * 2 + 1];
    float v = fmaxf(fmaf(f0.x, di, b2a.x), 0.f) * wpa.x
            + fmaxf(fmaf(f0.y, di, b2a.y), 0.f) * wpa.y
            + fmaxf(fmaf(f1.x, di, b2a.z), 0.f) * wpa.z
            + fmaxf(fmaf(f1.y, di, b2a.w), 0.f) * wpa.w
            + fmaxf(fmaf(f2.x, di, b2b.x), 0.f) * wpb.x
            + fmaxf(fmaf(f2.y, di, b2b.y), 0.f) * wpb.y
            + fmaxf(fmaf(f3.x, di, b2b.z), 0.f) * wpb.z
            + fmaxf(fmaf(f3.y, di, b2b.w), 0.f) * wpb.w;
    v += __shfl_xor(v, 1);                         // reduce the 8-lane group
    v += __shfl_xor(v, 2);
    v += __shfl_xor(v, 4);
    if (valid && f8 == 0) out[i] = 1.f / (1.f + expf(-(v + bp[0])));
}

extern "C" void kernel_launch(void* const* d_in, const int* in_sizes, int n_in,
                              void* d_out, int out_size, void* d_ws, size_t ws_size,
                              hipStream_t stream) {
    const float* x  = (const float*)d_in[0];
    const int*   ei = (const int*)d_in[1];   // [2, E] int32
    const float* W1 = (const float*)d_in[2];
    const float* b1 = (const float*)d_in[3];
    const float* W2 = (const float*)d_in[4];
    const float* b2 = (const float*)d_in[5];
    const float* Wp = (const float*)d_in[6];
    const float* bp = (const float*)d_in[7];
    float* out = (float*)d_out;

    int n = in_sizes[0] / 2;
    int E = in_sizes[1] / 2;
    const int* src = ei;
    const int* dst = ei + E;

    char* ws = (char*)d_ws;
    size_t off = 0;
    auto alloc = [&](size_t bytes) -> void* {
        void* p = ws + off;
        off += (bytes + 255) & ~(size_t)255;
        return p;
    };
    int nb = (n + SCAN_EPB - 1) / SCAN_EPB;
    int*    deg     = (int*)alloc((size_t)n * 4);
    int*    bsum    = (int*)alloc((size_t)nb * 4);
    int*    row_off = (int*)alloc((size_t)(n + 1) * 4);
    int*    cursor  = (int*)alloc((size_t)n * 4);
    float*  dinv    = (float*)alloc((size_t)n * 4);
    float2* xsc     = (float2*)alloc((size_t)n * 8);
    float2* xam     = (float2*)alloc((size_t)n * 8);
    int*    csr_src = (int*)alloc((size_t)E * 4);
    __half* w2t     = (__half*)alloc((size_t)128 * 64 * 2);
    __half* h1h     = (__half*)alloc((size_t)n * 128 * 2);
    __half* m2h     = (__half*)alloc((size_t)n * 64 * 2);
    (void)ws_size;

    hipMemsetAsync(deg, 0, (size_t)n * 4, stream);
    k_prepw    <<<32, 256, 0, stream>>>(W2, w2t);
    k_deg      <<<(E + 255) / 256, 256, 0, stream>>>(dst, deg, E);
    k_blocksum <<<nb, SCAN_TPB, 0, stream>>>(deg, bsum, n);
    k_scanbsum <<<1, 256, 0, stream>>>(bsum, row_off, nb, n);
    k_scanfinal<<<nb, SCAN_TPB, 0, stream>>>(deg, bsum, row_off, cursor, n);
    k_dinvx    <<<(n + 255) / 256, 256, 0, stream>>>(deg, x, dinv, xsc, n);
    k_fill     <<<(E + 255) / 256, 256, 0, stream>>>(src, dst, cursor, csr_src, E);
    k_agg1     <<<(n + 255) / 256, 256, 0, stream>>>(xsc, dinv, row_off, csr_src, xam, n);
    k_h1       <<<(n + 15) / 16, 256, 0, stream>>>(xam, W1, b1, h1h, n);
    k_gemm1m   <<<(n + 63) / 64, 256, 0, stream>>>(h1h, w2t, dinv, m2h, n);
    k_l2out    <<<(n + 31) / 32, 256, 0, stream>>>(m2h, dinv, row_off, csr_src,
                                                   b2, Wp, bp, out, n);
}

// Round 14
// 156.951 us; speedup vs baseline: 1.4122x; 1.0186x over previous
//
#include <hip/hip_runtime.h>
#include <hip/hip_fp16.h>
#include <math.h>

typedef _Float16 f16x8 __attribute__((ext_vector_type(8)));
typedef float f32x4 __attribute__((ext_vector_type(4)));

constexpr int SCAN_TPB = 256;
constexpr int SCAN_EPT = 8;                      // elements per thread
constexpr int SCAN_EPB = SCAN_TPB * SCAN_EPT;    // 2048 per block

// ---------------- init: W2 -> fp16 transposed [64][128]  +  zero deg ----------------
// Round-13 lesson: hipMemsetAsync(800KB) -> rocclr fillBuffer at 18.9 GB/s,
// 43 µs (27% of total). Zero it ourselves with a proper grid; fused with the
// tiny W2 transpose so no extra launch.
__global__ __launch_bounds__(256) void k_init(const float* __restrict__ W2,
                                              __half* __restrict__ w2t,
                                              int* __restrict__ deg, int n) {
    int idx = blockIdx.x * 256 + threadIdx.x;
    if (idx < 128 * 64) {
        int k = idx >> 6, f = idx & 63;
        w2t[f * 128 + k] = __float2half(W2[idx]);
    }
    int n4 = n >> 2;                               // int4 chunks
    int4* d4 = reinterpret_cast<int4*>(deg);
    int stride = gridDim.x * 256;
    for (int j = idx; j < n4; j += stride) d4[j] = make_int4(0, 0, 0, 0);
    for (int j = (n4 << 2) + idx; j < n; j += stride) deg[j] = 0;  // tail
}

// ---------------- degree (in-degree over dst) ----------------
__global__ void k_deg(const int* __restrict__ dst, int* __restrict__ deg, int E) {
    int i = blockIdx.x * blockDim.x + threadIdx.x;
    if (i < E) atomicAdd(&deg[dst[i]], 1);
}

// ---------------- scan phase A: per-block sums ----------------
__global__ __launch_bounds__(SCAN_TPB) void k_blocksum(const int* __restrict__ deg,
                                                       int* __restrict__ bsum, int n) {
    int t = threadIdx.x;
    int idx0 = blockIdx.x * SCAN_EPB + t * SCAN_EPT;
    int s = 0;
    if (idx0 + SCAN_EPT <= n) {
        const int4* p = reinterpret_cast<const int4*>(deg + idx0);
        int4 a = p[0], b = p[1];
        s = a.x + a.y + a.z + a.w + b.x + b.y + b.z + b.w;
    } else {
        for (int k = 0; k < SCAN_EPT; ++k) { int i = idx0 + k; if (i < n) s += deg[i]; }
    }
#pragma unroll
    for (int off = 32; off; off >>= 1) s += __shfl_xor(s, off);
    __shared__ int wsum[4];
    int lane = t & 63, wid = t >> 6;
    if (lane == 0) wsum[wid] = s;
    __syncthreads();
    if (t == 0) bsum[blockIdx.x] = wsum[0] + wsum[1] + wsum[2] + wsum[3];
}

// ---------------- scan phase B: exclusive-scan the block sums (tiny) ----------------
__global__ __launch_bounds__(256) void k_scanbsum(int* __restrict__ bsum,
                                                  int* __restrict__ row_off, int nb, int n) {
    int t = threadIdx.x, lane = t & 63, wid = t >> 6;
    __shared__ int wsum[4];
    int carry = 0;
    for (int base = 0; base < nb; base += 256) {
        int i = base + t;
        int v = (i < nb) ? bsum[i] : 0;
        int s = v;
#pragma unroll
        for (int off = 1; off < 64; off <<= 1) { int u = __shfl_up(s, off); if (lane >= off) s += u; }
        if (lane == 63) wsum[wid] = s;
        __syncthreads();
        int add = carry;
        for (int w = 0; w < wid; ++w) add += wsum[w];
        if (i < nb) bsum[i] = s - v + add;        // exclusive + carry
        carry += wsum[0] + wsum[1] + wsum[2] + wsum[3];
        __syncthreads();
    }
    if (t == 0) row_off[n] = carry;               // total edge count
}

// ---------------- scan phase C: final scan -> row_off/cursor, + fused dinv/xsc ------
// (dinv/xsc fused here: deg[i] is already in registers as e[k])
__global__ __launch_bounds__(SCAN_TPB) void k_scanfinal(const int* __restrict__ deg,
                                                        const int* __restrict__ bsum,
                                                        int* __restrict__ row_off,
                                                        int* __restrict__ cursor,
                                                        const float2* __restrict__ x2,
                                                        float* __restrict__ dinv,
                                                        float2* __restrict__ xsc, int n) {
    int t = threadIdx.x, lane = t & 63, wid = t >> 6;
    int idx0 = blockIdx.x * SCAN_EPB + t * SCAN_EPT;
    int e[SCAN_EPT];
    bool full = (idx0 + SCAN_EPT <= n);
    if (full) {
        const int4* p = reinterpret_cast<const int4*>(deg + idx0);
        int4 a = p[0], b = p[1];
        e[0] = a.x; e[1] = a.y; e[2] = a.z; e[3] = a.w;
        e[4] = b.x; e[5] = b.y; e[6] = b.z; e[7] = b.w;
    } else {
        for (int k = 0; k < SCAN_EPT; ++k) { int i = idx0 + k; e[k] = (i < n) ? deg[i] : 0; }
    }
    // fused dinv + xsc (coalesced within the thread's 8-elem chunk)
#pragma unroll
    for (int k = 0; k < SCAN_EPT; ++k) {
        int i = idx0 + k;
        if (i < n) {
            float di = rsqrtf((float)e[k] + 1.0f);  // +1 self loop
            dinv[i] = di;
            float2 xv = x2[i];
            xsc[i] = make_float2(xv.x * di, xv.y * di);
        }
    }
    int tsum = 0;
#pragma unroll
    for (int k = 0; k < SCAN_EPT; ++k) tsum += e[k];
    int s = tsum;
#pragma unroll
    for (int off = 1; off < 64; off <<= 1) { int u = __shfl_up(s, off); if (lane >= off) s += u; }
    __shared__ int wsum[4];
    if (lane == 63) wsum[wid] = s;
    __syncthreads();
    int add = bsum[blockIdx.x];
    for (int w = 0; w < wid; ++w) add += wsum[w];
    int run = s - tsum + add;                     // thread's exclusive prefix
    int o[SCAN_EPT];
#pragma unroll
    for (int k = 0; k < SCAN_EPT; ++k) { o[k] = run; run += e[k]; }
    if (full) {
        int4* ro = reinterpret_cast<int4*>(row_off + idx0);
        int4* cu = reinterpret_cast<int4*>(cursor + idx0);
        ro[0] = make_int4(o[0], o[1], o[2], o[3]);
        ro[1] = make_int4(o[4], o[5], o[6], o[7]);
        cu[0] = make_int4(o[0], o[1], o[2], o[3]);
        cu[1] = make_int4(o[4], o[5], o[6], o[7]);
    } else {
        for (int k = 0; k < SCAN_EPT; ++k) {
            int i = idx0 + k;
            if (i < n) { row_off[i] = o[k]; cursor[i] = o[k]; }
        }
    }
}

// ---------------- CSR fill (counting sort by dst) ----------------
__global__ void k_fill(const int* __restrict__ src, const int* __restrict__ dst,
                       int* __restrict__ cursor, int* __restrict__ csr_src, int E) {
    int e = blockIdx.x * blockDim.x + threadIdx.x;
    if (e < E) {
        int pos = atomicAdd(&cursor[dst[e]], 1);
        csr_src[pos] = src[e];
    }
}

// ---------------- layer-1 sparse aggregation: xam[i] = dinv[i]*(xsc[i] + sum_nbr xsc[s])
__global__ __launch_bounds__(256) void k_agg1(
    const float2* __restrict__ xsc, const float* __restrict__ dinv,
    const int* __restrict__ row_off, const int* __restrict__ csr_src,
    float2* __restrict__ xam, int n) {
    int i = blockIdx.x * blockDim.x + threadIdx.x;
    if (i >= n) return;
    int r0 = row_off[i], r1 = row_off[i + 1];
    float2 self = xsc[i];
    float xa0 = self.x, xa1 = self.y;
    for (int j = r0; j < r1; ++j) {
        float2 v = xsc[csr_src[j]];               // 8B gather, xsc=1.6MB L2-resident
        xa0 += v.x; xa1 += v.y;
    }
    float di = dinv[i];
    xam[i] = make_float2(xa0 * di, xa1 * di);
}

// ---------------- h1 = relu(xam@W1 + b1), fp16 [N][128] ----------------
__global__ __launch_bounds__(256) void k_h1(
    const float2* __restrict__ xam, const float* __restrict__ W1,
    const float* __restrict__ b1, __half* __restrict__ h1h, int n) {
    int tid = threadIdx.x;
    int nl = tid >> 4, ch = tid & 15;
    int i = blockIdx.x * 16 + nl;
    if (i >= n) return;
    float2 xa = xam[i];
    int k0 = ch * 8;
    float4 wa0 = *reinterpret_cast<const float4*>(&W1[k0]);
    float4 wa1 = *reinterpret_cast<const float4*>(&W1[k0 + 4]);
    float4 wb0 = *reinterpret_cast<const float4*>(&W1[128 + k0]);
    float4 wb1 = *reinterpret_cast<const float4*>(&W1[128 + k0 + 4]);
    float4 bb0 = *reinterpret_cast<const float4*>(&b1[k0]);
    float4 bb1 = *reinterpret_cast<const float4*>(&b1[k0 + 4]);
    float h0 = fmaxf(fmaf(xa.y, wb0.x, fmaf(xa.x, wa0.x, bb0.x)), 0.f);
    float h1 = fmaxf(fmaf(xa.y, wb0.y, fmaf(xa.x, wa0.y, bb0.y)), 0.f);
    float h2 = fmaxf(fmaf(xa.y, wb0.z, fmaf(xa.x, wa0.z, bb0.z)), 0.f);
    float h3 = fmaxf(fmaf(xa.y, wb0.w, fmaf(xa.x, wa0.w, bb0.w)), 0.f);
    float h4 = fmaxf(fmaf(xa.y, wb1.x, fmaf(xa.x, wa1.x, bb1.x)), 0.f);
    float h5 = fmaxf(fmaf(xa.y, wb1.y, fmaf(xa.x, wa1.y, bb1.y)), 0.f);
    float h6 = fmaxf(fmaf(xa.y, wb1.z, fmaf(xa.x, wa1.z, bb1.z)), 0.f);
    float h7 = fmaxf(fmaf(xa.y, wb1.w, fmaf(xa.x, wa1.w, bb1.w)), 0.f);
    union { __half2 h2v[4]; int4 q; } u;
    u.h2v[0] = __floats2half2_rn(h0, h1);
    u.h2v[1] = __floats2half2_rn(h2, h3);
    u.h2v[2] = __floats2half2_rn(h4, h5);
    u.h2v[3] = __floats2half2_rn(h6, h7);
    *reinterpret_cast<int4*>(h1h + (size_t)i * 128 + k0) = u.q;
}

// ---------------- layer-1 GEMM on MFMA: m2 = (h1 @ W2) * dinv, fp16 out ----------
__global__ __launch_bounds__(256, 2) void k_gemm1m(
    const __half* __restrict__ h1h, const __half* __restrict__ w2t,
    const float* __restrict__ dinv, __half* __restrict__ m2h, int n) {
    __shared__ __align__(16) float cs[4][16][68];
    int tid = threadIdx.x;
    int w = tid >> 6, lane = tid & 63;
    int col = lane & 15, kg = lane >> 4;
    int base = (blockIdx.x * 4 + w) * 16;          // 16 nodes per wave

    f16x8 bf[4][4];                                // B frags [f-tile][k-step]
#pragma unroll
    for (int ft = 0; ft < 4; ++ft)
#pragma unroll
        for (int t = 0; t < 4; ++t)
            bf[ft][t] = *reinterpret_cast<const f16x8*>(
                w2t + (ft * 16 + col) * 128 + t * 32 + kg * 8);

    int an = base + col; if (an >= n) an = 0;      // A row (clamped; store guarded)
    f32x4 c0 = {}, c1 = {}, c2 = {}, c3 = {};
#pragma unroll
    for (int t = 0; t < 4; ++t) {
        f16x8 a = *reinterpret_cast<const f16x8*>(
            h1h + (size_t)an * 128 + t * 32 + kg * 8);
        c0 = __builtin_amdgcn_mfma_f32_16x16x32_f16(a, bf[0][t], c0, 0, 0, 0);
        c1 = __builtin_amdgcn_mfma_f32_16x16x32_f16(a, bf[1][t], c1, 0, 0, 0);
        c2 = __builtin_amdgcn_mfma_f32_16x16x32_f16(a, bf[2][t], c2, 0, 0, 0);
        c3 = __builtin_amdgcn_mfma_f32_16x16x32_f16(a, bf[3][t], c3, 0, 0, 0);
    }
#pragma unroll
    for (int r = 0; r < 4; ++r) {                  // C row = kg*4+r, col = ft*16+col
        cs[w][kg * 4 + r][0 * 16 + col] = c0[r];
        cs[w][kg * 4 + r][1 * 16 + col] = c1[r];
        cs[w][kg * 4 + r][2 * 16 + col] = c2[r];
        cs[w][kg * 4 + r][3 * 16 + col] = c3[r];
    }
    __syncthreads();
    int nl = tid >> 2, ch = tid & 3;               // node-in-block, 16-feature chunk
    int node = blockIdx.x * 64 + nl;
    if (node < n) {
        float di = dinv[node];
        const float* row = &cs[nl >> 4][nl & 15][ch * 16];
        union { __half2 h2v[8]; int4 q[2]; } u;
#pragma unroll
        for (int j = 0; j < 8; ++j)
            u.h2v[j] = __floats2half2_rn(row[2 * j] * di, row[2 * j + 1] * di);
        int4* dst = reinterpret_cast<int4*>(m2h + (size_t)node * 64 + ch * 16);
        dst[0] = u.q[0]; dst[1] = u.q[1];
    }
}

// ---------------- layer 2 gather + full epilogue ----------------
// 8 nodes/wave, 8-lane group per node; packed fp16 accumulation; 3-shuffle
// group reduce.
__global__ __launch_bounds__(256) void k_l2out(
    const __half* __restrict__ m2h, const float* __restrict__ dinv,
    const int* __restrict__ row_off, const int* __restrict__ csr_src,
    const float* __restrict__ b2, const float* __restrict__ Wp,
    const float* __restrict__ bp, float* __restrict__ out, int n) {
    int tid = threadIdx.x;
    int wid = tid >> 6, lane = tid & 63;
    int g = lane >> 3;                             // node sub-slot 0..7
    int f8 = lane & 7;                             // feature octet 0..7
    int i = (blockIdx.x * 4 + wid) * 8 + g;
    bool valid = i < n;
    int ic = valid ? i : 0;
    int r0 = row_off[ic];
    int r1 = valid ? row_off[ic + 1] : r0;
    // self row initializes the accumulator (the +self term, exact)
    int4 sv = *reinterpret_cast<const int4*>(m2h + (size_t)ic * 64 + f8 * 8);
    const __half2* sh = reinterpret_cast<const __half2*>(&sv);
    __half2 a0 = sh[0], a1 = sh[1], a2 = sh[2], a3 = sh[3];
    for (int j = r0; j < r1; ++j) {                // serial per group; 8 chains/wave
        int s = csr_src[j];                        // uniform in group -> broadcast
        int4 v = *reinterpret_cast<const int4*>(m2h + (size_t)s * 64 + f8 * 8);
        const __half2* hv = reinterpret_cast<const __half2*>(&v);
        a0 = __hadd2(a0, hv[0]); a1 = __hadd2(a1, hv[1]);
        a2 = __hadd2(a2, hv[2]); a3 = __hadd2(a3, hv[3]);
    }
    float2 f0 = __half22float2(a0), f1 = __half22float2(a1);
    float2 f2 = __half22float2(a2), f3 = __half22float2(a3);
    float di = dinv[ic];
    float4 b2a = reinterpret_cast<const float4*>(b2)[f8 * 2];
    float4 b2b = reinterpret_cast<const float4*>(b2)[f8 * 2 + 1];
    float4 wpa = reinterpret_cast<const float4*>(Wp)[f8 * 2];
    float4 wpb = reinterpret_cast<const float4*>(Wp)[f8 * 2 + 1];
    float v = fmaxf(fmaf(f0.x, di, b2a.x), 0.f) * wpa.x
            + fmaxf(fmaf(f0.y, di, b2a.y), 0.f) * wpa.y
            + fmaxf(fmaf(f1.x, di, b2a.z), 0.f) * wpa.z
            + fmaxf(fmaf(f1.y, di, b2a.w), 0.f) * wpa.w
            + fmaxf(fmaf(f2.x, di, b2b.x), 0.f) * wpb.x
            + fmaxf(fmaf(f2.y, di, b2b.y), 0.f) * wpb.y
            + fmaxf(fmaf(f3.x, di, b2b.z), 0.f) * wpb.z
            + fmaxf(fmaf(f3.y, di, b2b.w), 0.f) * wpb.w;
    v += __shfl_xor(v, 1);                         // reduce the 8-lane group
    v += __shfl_xor(v, 2);
    v += __shfl_xor(v, 4);
    if (valid && f8 == 0) out[i] = 1.f / (1.f + expf(-(v + bp[0])));
}

extern "C" void kernel_launch(void* const* d_in, const int* in_sizes, int n_in,
                              void* d_out, int out_size, void* d_ws, size_t ws_size,
                              hipStream_t stream) {
    const float* x  = (const float*)d_in[0];
    const int*   ei = (const int*)d_in[1];   // [2, E] int32
    const float* W1 = (const float*)d_in[2];
    const float* b1 = (const float*)d_in[3];
    const float* W2 = (const float*)d_in[4];
    const float* b2 = (const float*)d_in[5];
    const float* Wp = (const float*)d_in[6];
    const float* bp = (const float*)d_in[7];
    float* out = (float*)d_out;

    int n = in_sizes[0] / 2;
    int E = in_sizes[1] / 2;
    const int* src = ei;
    const int* dst = ei + E;

    char* ws = (char*)d_ws;
    size_t off = 0;
    auto alloc = [&](size_t bytes) -> void* {
        void* p = ws + off;
        off += (bytes + 255) & ~(size_t)255;
        return p;
    };
    int nb = (n + SCAN_EPB - 1) / SCAN_EPB;
    int*    deg     = (int*)alloc((size_t)n * 4);
    int*    bsum    = (int*)alloc((size_t)nb * 4);
    int*    row_off = (int*)alloc((size_t)(n + 1) * 4);
    int*    cursor  = (int*)alloc((size_t)n * 4);
    float*  dinv    = (float*)alloc((size_t)n * 4);
    float2* xsc     = (float2*)alloc((size_t)n * 8);
    float2* xam     = (float2*)alloc((size_t)n * 8);
    int*    csr_src = (int*)alloc((size_t)E * 4);
    __half* w2t     = (__half*)alloc((size_t)128 * 64 * 2);
    __half* h1h     = (__half*)alloc((size_t)n * 128 * 2);
    __half* m2h     = (__half*)alloc((size_t)n * 64 * 2);
    (void)ws_size;

    k_init     <<<256, 256, 0, stream>>>(W2, w2t, deg, n);
    k_deg      <<<(E + 255) / 256, 256, 0, stream>>>(dst, deg, E);
    k_blocksum <<<nb, SCAN_TPB, 0, stream>>>(deg, bsum, n);
    k_scanbsum <<<1, 256, 0, stream>>>(bsum, row_off, nb, n);
    k_scanfinal<<<nb, SCAN_TPB, 0, stream>>>(deg, bsum, row_off, cursor,
                                             (const float2*)x, dinv, xsc, n);
    k_fill     <<<(E + 255) / 256, 256, 0, stream>>>(src, dst, cursor, csr_src, E);
    k_agg1     <<<(n + 255) / 256, 256, 0, stream>>>(xsc, dinv, row_off, csr_src, xam, n);
    k_h1       <<<(n + 15) / 16, 256, 0, stream>>>(xam, W1, b1, h1h, n);
    k_gemm1m   <<<(n + 63) / 64, 256, 0, stream>>>(h1h, w2t, dinv, m2h, n);
    k_l2out    <<<(n + 31) / 32, 256, 0, stream>>>(m2h, dinv, row_off, csr_src,
                                                   b2, Wp, bp, out, n);
}

// Round 15
// 145.725 us; speedup vs baseline: 1.5210x; 1.0770x over previous
//
#include <hip/hip_runtime.h>
#include <hip/hip_fp16.h>
#include <math.h>

typedef _Float16 f16x8 __attribute__((ext_vector_type(8)));
typedef float f32x4 __attribute__((ext_vector_type(4)));

constexpr int SCAN_TPB = 256;
constexpr int SCAN_EPT = 8;                      // elements per thread
constexpr int SCAN_EPB = SCAN_TPB * SCAN_EPT;    // 2048 per block

// ---------------- init: W2 -> fp16 transposed [64][128]  +  zero deg ----------------
__global__ __launch_bounds__(256) void k_init(const float* __restrict__ W2,
                                              __half* __restrict__ w2t,
                                              int* __restrict__ deg, int n) {
    int idx = blockIdx.x * 256 + threadIdx.x;
    if (idx < 128 * 64) {
        int k = idx >> 6, f = idx & 63;
        w2t[f * 128 + k] = __float2half(W2[idx]);
    }
    int n4 = n >> 2;                               // int4 chunks
    int4* d4 = reinterpret_cast<int4*>(deg);
    int stride = gridDim.x * 256;
    for (int j = idx; j < n4; j += stride) d4[j] = make_int4(0, 0, 0, 0);
    for (int j = (n4 << 2) + idx; j < n; j += stride) deg[j] = 0;  // tail
}

// ---------------- degree (in-degree over dst) ----------------
__global__ void k_deg(const int* __restrict__ dst, int* __restrict__ deg, int E) {
    int i = blockIdx.x * blockDim.x + threadIdx.x;
    if (i < E) atomicAdd(&deg[dst[i]], 1);
}

// ---------------- scan phase A: per-block sums ----------------
__global__ __launch_bounds__(SCAN_TPB) void k_blocksum(const int* __restrict__ deg,
                                                       int* __restrict__ bsum, int n) {
    int t = threadIdx.x;
    int idx0 = blockIdx.x * SCAN_EPB + t * SCAN_EPT;
    int s = 0;
    if (idx0 + SCAN_EPT <= n) {
        const int4* p = reinterpret_cast<const int4*>(deg + idx0);
        int4 a = p[0], b = p[1];
        s = a.x + a.y + a.z + a.w + b.x + b.y + b.z + b.w;
    } else {
        for (int k = 0; k < SCAN_EPT; ++k) { int i = idx0 + k; if (i < n) s += deg[i]; }
    }
#pragma unroll
    for (int off = 32; off; off >>= 1) s += __shfl_xor(s, off);
    __shared__ int wsum[4];
    int lane = t & 63, wid = t >> 6;
    if (lane == 0) wsum[wid] = s;
    __syncthreads();
    if (t == 0) bsum[blockIdx.x] = wsum[0] + wsum[1] + wsum[2] + wsum[3];
}

// ---------------- scan phase B: exclusive-scan the block sums (tiny) ----------------
__global__ __launch_bounds__(256) void k_scanbsum(int* __restrict__ bsum,
                                                  int* __restrict__ row_off, int nb, int n) {
    int t = threadIdx.x, lane = t & 63, wid = t >> 6;
    __shared__ int wsum[4];
    int carry = 0;
    for (int base = 0; base < nb; base += 256) {
        int i = base + t;
        int v = (i < nb) ? bsum[i] : 0;
        int s = v;
#pragma unroll
        for (int off = 1; off < 64; off <<= 1) { int u = __shfl_up(s, off); if (lane >= off) s += u; }
        if (lane == 63) wsum[wid] = s;
        __syncthreads();
        int add = carry;
        for (int w = 0; w < wid; ++w) add += wsum[w];
        if (i < nb) bsum[i] = s - v + add;        // exclusive + carry
        carry += wsum[0] + wsum[1] + wsum[2] + wsum[3];
        __syncthreads();
    }
    if (t == 0) row_off[n] = carry;               // total edge count
}

// ---------------- scan phase C: final scan -> row_off/cursor, + fused dinv/xsc ------
__global__ __launch_bounds__(SCAN_TPB) void k_scanfinal(const int* __restrict__ deg,
                                                        const int* __restrict__ bsum,
                                                        int* __restrict__ row_off,
                                                        int* __restrict__ cursor,
                                                        const float2* __restrict__ x2,
                                                        float* __restrict__ dinv,
                                                        float2* __restrict__ xsc, int n) {
    int t = threadIdx.x, lane = t & 63, wid = t >> 6;
    int idx0 = blockIdx.x * SCAN_EPB + t * SCAN_EPT;
    int e[SCAN_EPT];
    bool full = (idx0 + SCAN_EPT <= n);
    if (full) {
        const int4* p = reinterpret_cast<const int4*>(deg + idx0);
        int4 a = p[0], b = p[1];
        e[0] = a.x; e[1] = a.y; e[2] = a.z; e[3] = a.w;
        e[4] = b.x; e[5] = b.y; e[6] = b.z; e[7] = b.w;
    } else {
        for (int k = 0; k < SCAN_EPT; ++k) { int i = idx0 + k; e[k] = (i < n) ? deg[i] : 0; }
    }
    // fused dinv + xsc (coalesced within the thread's 8-elem chunk)
#pragma unroll
    for (int k = 0; k < SCAN_EPT; ++k) {
        int i = idx0 + k;
        if (i < n) {
            float di = rsqrtf((float)e[k] + 1.0f);  // +1 self loop
            dinv[i] = di;
            float2 xv = x2[i];
            xsc[i] = make_float2(xv.x * di, xv.y * di);
        }
    }
    int tsum = 0;
#pragma unroll
    for (int k = 0; k < SCAN_EPT; ++k) tsum += e[k];
    int s = tsum;
#pragma unroll
    for (int off = 1; off < 64; off <<= 1) { int u = __shfl_up(s, off); if (lane >= off) s += u; }
    __shared__ int wsum[4];
    if (lane == 63) wsum[wid] = s;
    __syncthreads();
    int add = bsum[blockIdx.x];
    for (int w = 0; w < wid; ++w) add += wsum[w];
    int run = s - tsum + add;                     // thread's exclusive prefix
    int o[SCAN_EPT];
#pragma unroll
    for (int k = 0; k < SCAN_EPT; ++k) { o[k] = run; run += e[k]; }
    if (full) {
        int4* ro = reinterpret_cast<int4*>(row_off + idx0);
        int4* cu = reinterpret_cast<int4*>(cursor + idx0);
        ro[0] = make_int4(o[0], o[1], o[2], o[3]);
        ro[1] = make_int4(o[4], o[5], o[6], o[7]);
        cu[0] = make_int4(o[0], o[1], o[2], o[3]);
        cu[1] = make_int4(o[4], o[5], o[6], o[7]);
    } else {
        for (int k = 0; k < SCAN_EPT; ++k) {
            int i = idx0 + k;
            if (i < n) { row_off[i] = o[k]; cursor[i] = o[k]; }
        }
    }
}

// ---------------- CSR fill (counting sort by dst) ----------------
__global__ void k_fill(const int* __restrict__ src, const int* __restrict__ dst,
                       int* __restrict__ cursor, int* __restrict__ csr_src, int E) {
    int e = blockIdx.x * blockDim.x + threadIdx.x;
    if (e < E) {
        int pos = atomicAdd(&cursor[dst[e]], 1);
        csr_src[pos] = src[e];
    }
}

// ---------------- layer-1 sparse aggregation: xam[i] = dinv[i]*(xsc[i] + sum_nbr xsc[s])
__global__ __launch_bounds__(256) void k_agg1(
    const float2* __restrict__ xsc, const float* __restrict__ dinv,
    const int* __restrict__ row_off, const int* __restrict__ csr_src,
    float2* __restrict__ xam, int n) {
    int i = blockIdx.x * blockDim.x + threadIdx.x;
    if (i >= n) return;
    int r0 = row_off[i], r1 = row_off[i + 1];
    float2 self = xsc[i];
    float xa0 = self.x, xa1 = self.y;
    for (int j = r0; j < r1; ++j) {
        float2 v = xsc[csr_src[j]];               // 8B gather, xsc=1.6MB L2-resident
        xa0 += v.x; xa1 += v.y;
    }
    float di = dinv[i];
    xam[i] = make_float2(xa0 * di, xa1 * di);
}

// ---------------- layer-1 fused MLP on MFMA: m2 = (relu(xam@W1+b1) @ W2) * dinv -----
// Round-14 lesson: h1h (51MB) was written then immediately re-read -- 102MB of
// HBM for data derivable from 2 floats/node. A-fragments are now computed on
// the fly: lane (col,kg) builds its 8 h-values per t-step from xam[node] and
// L1-resident W1/b1 slices (~112 VALU/lane, hidden under MFMA issue).
__global__ __launch_bounds__(256, 2) void k_gemm1m(
    const float2* __restrict__ xam, const float* __restrict__ W1,
    const float* __restrict__ b1, const __half* __restrict__ w2t,
    const float* __restrict__ dinv, __half* __restrict__ m2h, int n) {
    __shared__ __align__(16) float cs[4][16][68];
    int tid = threadIdx.x;
    int w = tid >> 6, lane = tid & 63;
    int col = lane & 15, kg = lane >> 4;
    int base = (blockIdx.x * 4 + w) * 16;          // 16 nodes per wave

    f16x8 bf[4][4];                                // B frags [f-tile][k-step]
#pragma unroll
    for (int ft = 0; ft < 4; ++ft)
#pragma unroll
        for (int t = 0; t < 4; ++t)
            bf[ft][t] = *reinterpret_cast<const f16x8*>(
                w2t + (ft * 16 + col) * 128 + t * 32 + kg * 8);

    int an = base + col; if (an >= n) an = 0;      // A row (clamped; store guarded)
    float2 xa = xam[an];
    f32x4 c0 = {}, c1 = {}, c2 = {}, c3 = {};
#pragma unroll
    for (int t = 0; t < 4; ++t) {
        int k0 = t * 32 + kg * 8;
        float4 wa0 = *reinterpret_cast<const float4*>(&W1[k0]);
        float4 wa1 = *reinterpret_cast<const float4*>(&W1[k0 + 4]);
        float4 wb0 = *reinterpret_cast<const float4*>(&W1[128 + k0]);
        float4 wb1 = *reinterpret_cast<const float4*>(&W1[128 + k0 + 4]);
        float4 bb0 = *reinterpret_cast<const float4*>(&b1[k0]);
        float4 bb1 = *reinterpret_cast<const float4*>(&b1[k0 + 4]);
        f16x8 a;
        a[0] = (_Float16)fmaxf(fmaf(xa.y, wb0.x, fmaf(xa.x, wa0.x, bb0.x)), 0.f);
        a[1] = (_Float16)fmaxf(fmaf(xa.y, wb0.y, fmaf(xa.x, wa0.y, bb0.y)), 0.f);
        a[2] = (_Float16)fmaxf(fmaf(xa.y, wb0.z, fmaf(xa.x, wa0.z, bb0.z)), 0.f);
        a[3] = (_Float16)fmaxf(fmaf(xa.y, wb0.w, fmaf(xa.x, wa0.w, bb0.w)), 0.f);
        a[4] = (_Float16)fmaxf(fmaf(xa.y, wb1.x, fmaf(xa.x, wa1.x, bb1.x)), 0.f);
        a[5] = (_Float16)fmaxf(fmaf(xa.y, wb1.y, fmaf(xa.x, wa1.y, bb1.y)), 0.f);
        a[6] = (_Float16)fmaxf(fmaf(xa.y, wb1.z, fmaf(xa.x, wa1.z, bb1.z)), 0.f);
        a[7] = (_Float16)fmaxf(fmaf(xa.y, wb1.w, fmaf(xa.x, wa1.w, bb1.w)), 0.f);
        c0 = __builtin_amdgcn_mfma_f32_16x16x32_f16(a, bf[0][t], c0, 0, 0, 0);
        c1 = __builtin_amdgcn_mfma_f32_16x16x32_f16(a, bf[1][t], c1, 0, 0, 0);
        c2 = __builtin_amdgcn_mfma_f32_16x16x32_f16(a, bf[2][t], c2, 0, 0, 0);
        c3 = __builtin_amdgcn_mfma_f32_16x16x32_f16(a, bf[3][t], c3, 0, 0, 0);
    }
#pragma unroll
    for (int r = 0; r < 4; ++r) {                  // C row = kg*4+r, col = ft*16+col
        cs[w][kg * 4 + r][0 * 16 + col] = c0[r];
        cs[w][kg * 4 + r][1 * 16 + col] = c1[r];
        cs[w][kg * 4 + r][2 * 16 + col] = c2[r];
        cs[w][kg * 4 + r][3 * 16 + col] = c3[r];
    }
    __syncthreads();
    int nl = tid >> 2, ch = tid & 3;               // node-in-block, 16-feature chunk
    int node = blockIdx.x * 64 + nl;
    if (node < n) {
        float di = dinv[node];
        const float* row = &cs[nl >> 4][nl & 15][ch * 16];
        union { __half2 h2v[8]; int4 q[2]; } u;
#pragma unroll
        for (int j = 0; j < 8; ++j)
            u.h2v[j] = __floats2half2_rn(row[2 * j] * di, row[2 * j + 1] * di);
        int4* dst = reinterpret_cast<int4*>(m2h + (size_t)node * 64 + ch * 16);
        dst[0] = u.q[0]; dst[1] = u.q[1];
    }
}

// ---------------- layer 2 gather + full epilogue ----------------
// 8 nodes/wave, 8-lane group per node; packed fp16 accumulation; 3-shuffle
// group reduce.
__global__ __launch_bounds__(256) void k_l2out(
    const __half* __restrict__ m2h, const float* __restrict__ dinv,
    const int* __restrict__ row_off, const int* __restrict__ csr_src,
    const float* __restrict__ b2, const float* __restrict__ Wp,
    const float* __restrict__ bp, float* __restrict__ out, int n) {
    int tid = threadIdx.x;
    int wid = tid >> 6, lane = tid & 63;
    int g = lane >> 3;                             // node sub-slot 0..7
    int f8 = lane & 7;                             // feature octet 0..7
    int i = (blockIdx.x * 4 + wid) * 8 + g;
    bool valid = i < n;
    int ic = valid ? i : 0;
    int r0 = row_off[ic];
    int r1 = valid ? row_off[ic + 1] : r0;
    // self row initializes the accumulator (the +self term, exact)
    int4 sv = *reinterpret_cast<const int4*>(m2h + (size_t)ic * 64 + f8 * 8);
    const __half2* sh = reinterpret_cast<const __half2*>(&sv);
    __half2 a0 = sh[0], a1 = sh[1], a2 = sh[2], a3 = sh[3];
    for (int j = r0; j < r1; ++j) {                // serial per group; 8 chains/wave
        int s = csr_src[j];                        // uniform in group -> broadcast
        int4 v = *reinterpret_cast<const int4*>(m2h + (size_t)s * 64 + f8 * 8);
        const __half2* hv = reinterpret_cast<const __half2*>(&v);
        a0 = __hadd2(a0, hv[0]); a1 = __hadd2(a1, hv[1]);
        a2 = __hadd2(a2, hv[2]); a3 = __hadd2(a3, hv[3]);
    }
    float2 f0 = __half22float2(a0), f1 = __half22float2(a1);
    float2 f2 = __half22float2(a2), f3 = __half22float2(a3);
    float di = dinv[ic];
    float4 b2a = reinterpret_cast<const float4*>(b2)[f8 * 2];
    float4 b2b = reinterpret_cast<const float4*>(b2)[f8 * 2 + 1];
    float4 wpa = reinterpret_cast<const float4*>(Wp)[f8 * 2];
    float4 wpb = reinterpret_cast<const float4*>(Wp)[f8 * 2 + 1];
    float v = fmaxf(fmaf(f0.x, di, b2a.x), 0.f) * wpa.x
            + fmaxf(fmaf(f0.y, di, b2a.y), 0.f) * wpa.y
            + fmaxf(fmaf(f1.x, di, b2a.z), 0.f) * wpa.z
            + fmaxf(fmaf(f1.y, di, b2a.w), 0.f) * wpa.w
            + fmaxf(fmaf(f2.x, di, b2b.x), 0.f) * wpb.x
            + fmaxf(fmaf(f2.y, di, b2b.y), 0.f) * wpb.y
            + fmaxf(fmaf(f3.x, di, b2b.z), 0.f) * wpb.z
            + fmaxf(fmaf(f3.y, di, b2b.w), 0.f) * wpb.w;
    v += __shfl_xor(v, 1);                         // reduce the 8-lane group
    v += __shfl_xor(v, 2);
    v += __shfl_xor(v, 4);
    if (valid && f8 == 0) out[i] = 1.f / (1.f + expf(-(v + bp[0])));
}

extern "C" void kernel_launch(void* const* d_in, const int* in_sizes, int n_in,
                              void* d_out, int out_size, void* d_ws, size_t ws_size,
                              hipStream_t stream) {
    const float* x  = (const float*)d_in[0];
    const int*   ei = (const int*)d_in[1];   // [2, E] int32
    const float* W1 = (const float*)d_in[2];
    const float* b1 = (const float*)d_in[3];
    const float* W2 = (const float*)d_in[4];
    const float* b2 = (const float*)d_in[5];
    const float* Wp = (const float*)d_in[6];
    const float* bp = (const float*)d_in[7];
    float* out = (float*)d_out;

    int n = in_sizes[0] / 2;
    int E = in_sizes[1] / 2;
    const int* src = ei;
    const int* dst = ei + E;

    char* ws = (char*)d_ws;
    size_t off = 0;
    auto alloc = [&](size_t bytes) -> void* {
        void* p = ws + off;
        off += (bytes + 255) & ~(size_t)255;
        return p;
    };
    int nb = (n + SCAN_EPB - 1) / SCAN_EPB;
    int*    deg     = (int*)alloc((size_t)n * 4);
    int*    bsum    = (int*)alloc((size_t)nb * 4);
    int*    row_off = (int*)alloc((size_t)(n + 1) * 4);
    int*    cursor  = (int*)alloc((size_t)n * 4);
    float*  dinv    = (float*)alloc((size_t)n * 4);
    float2* xsc     = (float2*)alloc((size_t)n * 8);
    float2* xam     = (float2*)alloc((size_t)n * 8);
    int*    csr_src = (int*)alloc((size_t)E * 4);
    __half* w2t     = (__half*)alloc((size_t)128 * 64 * 2);
    __half* m2h     = (__half*)alloc((size_t)n * 64 * 2);
    (void)ws_size;

    k_init     <<<256, 256, 0, stream>>>(W2, w2t, deg, n);
    k_deg      <<<(E + 255) / 256, 256, 0, stream>>>(dst, deg, E);
    k_blocksum <<<nb, SCAN_TPB, 0, stream>>>(deg, bsum, n);
    k_scanbsum <<<1, 256, 0, stream>>>(bsum, row_off, nb, n);
    k_scanfinal<<<nb, SCAN_TPB, 0, stream>>>(deg, bsum, row_off, cursor,
                                             (const float2*)x, dinv, xsc, n);
    k_fill     <<<(E + 255) / 256, 256, 0, stream>>>(src, dst, cursor, csr_src, E);
    k_agg1     <<<(n + 255) / 256, 256, 0, stream>>>(xsc, dinv, row_off, csr_src, xam, n);
    k_gemm1m   <<<(n + 63) / 64, 256, 0, stream>>>(xam, W1, b1, w2t, dinv, m2h, n);
    k_l2out    <<<(n + 31) / 32, 256, 0, stream>>>(m2h, dinv, row_off, csr_src,
                                                   b2, Wp, bp, out, n);
}

// Round 16
// 141.019 us; speedup vs baseline: 1.5718x; 1.0334x over previous
//
#include <hip/hip_runtime.h>
#include <hip/hip_fp16.h>
#include <math.h>

typedef _Float16 f16x8 __attribute__((ext_vector_type(8)));
typedef float f32x4 __attribute__((ext_vector_type(4)));

constexpr int SCAN_TPB = 256;
constexpr int SCAN_EPT = 8;                      // elements per thread
constexpr int SCAN_EPB = SCAN_TPB * SCAN_EPT;    // 2048 per block

// ---------------- init: W2 -> fp16 transposed [64][128]  +  zero deg ----------------
__global__ __launch_bounds__(256) void k_init(const float* __restrict__ W2,
                                              __half* __restrict__ w2t,
                                              int* __restrict__ deg, int n) {
    int idx = blockIdx.x * 256 + threadIdx.x;
    if (idx < 128 * 64) {
        int k = idx >> 6, f = idx & 63;
        w2t[f * 128 + k] = __float2half(W2[idx]);
    }
    int n4 = n >> 2;                               // int4 chunks
    int4* d4 = reinterpret_cast<int4*>(deg);
    int stride = gridDim.x * 256;
    for (int j = idx; j < n4; j += stride) d4[j] = make_int4(0, 0, 0, 0);
    for (int j = (n4 << 2) + idx; j < n; j += stride) deg[j] = 0;  // tail
}

// ---------------- degree (in-degree over dst) ----------------
__global__ void k_deg(const int* __restrict__ dst, int* __restrict__ deg, int E) {
    int i = blockIdx.x * blockDim.x + threadIdx.x;
    if (i < E) atomicAdd(&deg[dst[i]], 1);
}

// ---------------- scan phase A: per-block sums (raw, not scanned) ----------------
__global__ __launch_bounds__(SCAN_TPB) void k_blocksum(const int* __restrict__ deg,
                                                       int* __restrict__ bsum, int n) {
    int t = threadIdx.x;
    int idx0 = blockIdx.x * SCAN_EPB + t * SCAN_EPT;
    int s = 0;
    if (idx0 + SCAN_EPT <= n) {
        const int4* p = reinterpret_cast<const int4*>(deg + idx0);
        int4 a = p[0], b = p[1];
        s = a.x + a.y + a.z + a.w + b.x + b.y + b.z + b.w;
    } else {
        for (int k = 0; k < SCAN_EPT; ++k) { int i = idx0 + k; if (i < n) s += deg[i]; }
    }
#pragma unroll
    for (int off = 32; off; off >>= 1) s += __shfl_xor(s, off);
    __shared__ int wsum[4];
    int lane = t & 63, wid = t >> 6;
    if (lane == 0) wsum[wid] = s;
    __syncthreads();
    if (t == 0) bsum[blockIdx.x] = wsum[0] + wsum[1] + wsum[2] + wsum[3];
}

// ---------------- scan phase B (fused): final scan -> row_off/cursor + dinv/xsc -----
// Round-16: the serial 1-block k_scanbsum kernel (plus a launch gap) is gone;
// each block computes its own offset = sum(bsum[j<bid]) in parallel (<=98 elems),
// the last block also writes row_off[n].
__global__ __launch_bounds__(SCAN_TPB) void k_scanfinal(const int* __restrict__ deg,
                                                        const int* __restrict__ bsum,
                                                        int nb,
                                                        int* __restrict__ row_off,
                                                        int* __restrict__ cursor,
                                                        const float2* __restrict__ x2,
                                                        float* __restrict__ dinv,
                                                        float2* __restrict__ xsc, int n) {
    int t = threadIdx.x, lane = t & 63, wid = t >> 6;
    __shared__ int wsumA[4], wsumB[4], wsumC[4];
    __shared__ int s_add;
    int bid = blockIdx.x;
    int partial = 0;                               // block offset: sum of bsum[j<bid]
    for (int j = t; j < bid; j += SCAN_TPB) partial += bsum[j];
#pragma unroll
    for (int off = 32; off; off >>= 1) partial += __shfl_xor(partial, off);
    if (lane == 0) wsumA[wid] = partial;
    if (bid == (int)gridDim.x - 1) {               // grand total -> row_off[n]
        int tot = 0;
        for (int j = t; j < nb; j += SCAN_TPB) tot += bsum[j];
#pragma unroll
        for (int off = 32; off; off >>= 1) tot += __shfl_xor(tot, off);
        if (lane == 0) wsumB[wid] = tot;
    }
    __syncthreads();
    if (t == 0) {
        s_add = wsumA[0] + wsumA[1] + wsumA[2] + wsumA[3];
        if (bid == (int)gridDim.x - 1)
            row_off[n] = wsumB[0] + wsumB[1] + wsumB[2] + wsumB[3];
    }

    int idx0 = bid * SCAN_EPB + t * SCAN_EPT;
    int e[SCAN_EPT];
    bool full = (idx0 + SCAN_EPT <= n);
    if (full) {
        const int4* p = reinterpret_cast<const int4*>(deg + idx0);
        int4 a = p[0], b = p[1];
        e[0] = a.x; e[1] = a.y; e[2] = a.z; e[3] = a.w;
        e[4] = b.x; e[5] = b.y; e[6] = b.z; e[7] = b.w;
    } else {
        for (int k = 0; k < SCAN_EPT; ++k) { int i = idx0 + k; e[k] = (i < n) ? deg[i] : 0; }
    }
    // fused dinv + xsc (coalesced within the thread's 8-elem chunk)
#pragma unroll
    for (int k = 0; k < SCAN_EPT; ++k) {
        int i = idx0 + k;
        if (i < n) {
            float di = rsqrtf((float)e[k] + 1.0f);  // +1 self loop
            dinv[i] = di;
            float2 xv = x2[i];
            xsc[i] = make_float2(xv.x * di, xv.y * di);
        }
    }
    int tsum = 0;
#pragma unroll
    for (int k = 0; k < SCAN_EPT; ++k) tsum += e[k];
    int s = tsum;
#pragma unroll
    for (int off = 1; off < 64; off <<= 1) { int u = __shfl_up(s, off); if (lane >= off) s += u; }
    if (lane == 63) wsumC[wid] = s;
    __syncthreads();
    int add = s_add;
    for (int w = 0; w < wid; ++w) add += wsumC[w];
    int run = s - tsum + add;                     // thread's exclusive prefix
    int o[SCAN_EPT];
#pragma unroll
    for (int k = 0; k < SCAN_EPT; ++k) { o[k] = run; run += e[k]; }
    if (full) {
        int4* ro = reinterpret_cast<int4*>(row_off + idx0);
        int4* cu = reinterpret_cast<int4*>(cursor + idx0);
        ro[0] = make_int4(o[0], o[1], o[2], o[3]);
        ro[1] = make_int4(o[4], o[5], o[6], o[7]);
        cu[0] = make_int4(o[0], o[1], o[2], o[3]);
        cu[1] = make_int4(o[4], o[5], o[6], o[7]);
    } else {
        for (int k = 0; k < SCAN_EPT; ++k) {
            int i = idx0 + k;
            if (i < n) { row_off[i] = o[k]; cursor[i] = o[k]; }
        }
    }
}

// ---------------- CSR fill (counting sort by dst) ----------------
__global__ void k_fill(const int* __restrict__ src, const int* __restrict__ dst,
                       int* __restrict__ cursor, int* __restrict__ csr_src, int E) {
    int e = blockIdx.x * blockDim.x + threadIdx.x;
    if (e < E) {
        int pos = atomicAdd(&cursor[dst[e]], 1);
        csr_src[pos] = src[e];
    }
}

// ---------------- layer-1 sparse aggregation: xam[i] = dinv[i]*(xsc[i] + sum_nbr xsc[s])
__global__ __launch_bounds__(256) void k_agg1(
    const float2* __restrict__ xsc, const float* __restrict__ dinv,
    const int* __restrict__ row_off, const int* __restrict__ csr_src,
    float2* __restrict__ xam, int n) {
    int i = blockIdx.x * blockDim.x + threadIdx.x;
    if (i >= n) return;
    int r0 = row_off[i], r1 = row_off[i + 1];
    float2 self = xsc[i];
    float xa0 = self.x, xa1 = self.y;
    for (int j = r0; j < r1; ++j) {
        float2 v = xsc[csr_src[j]];               // 8B gather, xsc=1.6MB L2-resident
        xa0 += v.x; xa1 += v.y;
    }
    float di = dinv[i];
    xam[i] = make_float2(xa0 * di, xa1 * di);
}

// ---------------- layer-1 fused MLP on MFMA: m2 = (relu(xam@W1+b1) @ W2) * dinv -----
__global__ __launch_bounds__(256, 2) void k_gemm1m(
    const float2* __restrict__ xam, const float* __restrict__ W1,
    const float* __restrict__ b1, const __half* __restrict__ w2t,
    const float* __restrict__ dinv, __half* __restrict__ m2h, int n) {
    __shared__ __align__(16) float cs[4][16][68];
    int tid = threadIdx.x;
    int w = tid >> 6, lane = tid & 63;
    int col = lane & 15, kg = lane >> 4;
    int base = (blockIdx.x * 4 + w) * 16;          // 16 nodes per wave

    f16x8 bf[4][4];                                // B frags [f-tile][k-step]
#pragma unroll
    for (int ft = 0; ft < 4; ++ft)
#pragma unroll
        for (int t = 0; t < 4; ++t)
            bf[ft][t] = *reinterpret_cast<const f16x8*>(
                w2t + (ft * 16 + col) * 128 + t * 32 + kg * 8);

    int an = base + col; if (an >= n) an = 0;      // A row (clamped; store guarded)
    float2 xa = xam[an];
    f32x4 c0 = {}, c1 = {}, c2 = {}, c3 = {};
#pragma unroll
    for (int t = 0; t < 4; ++t) {
        int k0 = t * 32 + kg * 8;
        float4 wa0 = *reinterpret_cast<const float4*>(&W1[k0]);
        float4 wa1 = *reinterpret_cast<const float4*>(&W1[k0 + 4]);
        float4 wb0 = *reinterpret_cast<const float4*>(&W1[128 + k0]);
        float4 wb1 = *reinterpret_cast<const float4*>(&W1[128 + k0 + 4]);
        float4 bb0 = *reinterpret_cast<const float4*>(&b1[k0]);
        float4 bb1 = *reinterpret_cast<const float4*>(&b1[k0 + 4]);
        f16x8 a;
        a[0] = (_Float16)fmaxf(fmaf(xa.y, wb0.x, fmaf(xa.x, wa0.x, bb0.x)), 0.f);
        a[1] = (_Float16)fmaxf(fmaf(xa.y, wb0.y, fmaf(xa.x, wa0.y, bb0.y)), 0.f);
        a[2] = (_Float16)fmaxf(fmaf(xa.y, wb0.z, fmaf(xa.x, wa0.z, bb0.z)), 0.f);
        a[3] = (_Float16)fmaxf(fmaf(xa.y, wb0.w, fmaf(xa.x, wa0.w, bb0.w)), 0.f);
        a[4] = (_Float16)fmaxf(fmaf(xa.y, wb1.x, fmaf(xa.x, wa1.x, bb1.x)), 0.f);
        a[5] = (_Float16)fmaxf(fmaf(xa.y, wb1.y, fmaf(xa.x, wa1.y, bb1.y)), 0.f);
        a[6] = (_Float16)fmaxf(fmaf(xa.y, wb1.z, fmaf(xa.x, wa1.z, bb1.z)), 0.f);
        a[7] = (_Float16)fmaxf(fmaf(xa.y, wb1.w, fmaf(xa.x, wa1.w, bb1.w)), 0.f);
        c0 = __builtin_amdgcn_mfma_f32_16x16x32_f16(a, bf[0][t], c0, 0, 0, 0);
        c1 = __builtin_amdgcn_mfma_f32_16x16x32_f16(a, bf[1][t], c1, 0, 0, 0);
        c2 = __builtin_amdgcn_mfma_f32_16x16x32_f16(a, bf[2][t], c2, 0, 0, 0);
        c3 = __builtin_amdgcn_mfma_f32_16x16x32_f16(a, bf[3][t], c3, 0, 0, 0);
    }
#pragma unroll
    for (int r = 0; r < 4; ++r) {                  // C row = kg*4+r, col = ft*16+col
        cs[w][kg * 4 + r][0 * 16 + col] = c0[r];
        cs[w][kg * 4 + r][1 * 16 + col] = c1[r];
        cs[w][kg * 4 + r][2 * 16 + col] = c2[r];
        cs[w][kg * 4 + r][3 * 16 + col] = c3[r];
    }
    __syncthreads();
    int nl = tid >> 2, ch = tid & 3;               // node-in-block, 16-feature chunk
    int node = blockIdx.x * 64 + nl;
    if (node < n) {
        float di = dinv[node];
        const float* row = &cs[nl >> 4][nl & 15][ch * 16];
        union { __half2 h2v[8]; int4 q[2]; } u;
#pragma unroll
        for (int j = 0; j < 8; ++j)
            u.h2v[j] = __floats2half2_rn(row[2 * j] * di, row[2 * j + 1] * di);
        int4* dst = reinterpret_cast<int4*>(m2h + (size_t)node * 64 + ch * 16);
        dst[0] = u.q[0]; dst[1] = u.q[1];
    }
}

// ---------------- layer 2 gather + full epilogue ----------------
// 8 nodes/wave, 8-lane group per node; packed fp16 accumulation. Round-16:
// edge loop unrolled x2 with dual accumulator sets -> 2 row-gathers in flight
// per group (was a fully serial dependent chain).
__global__ __launch_bounds__(256) void k_l2out(
    const __half* __restrict__ m2h, const float* __restrict__ dinv,
    const int* __restrict__ row_off, const int* __restrict__ csr_src,
    const float* __restrict__ b2, const float* __restrict__ Wp,
    const float* __restrict__ bp, float* __restrict__ out, int n) {
    int tid = threadIdx.x;
    int wid = tid >> 6, lane = tid & 63;
    int g = lane >> 3;                             // node sub-slot 0..7
    int f8 = lane & 7;                             // feature octet 0..7
    int i = (blockIdx.x * 4 + wid) * 8 + g;
    bool valid = i < n;
    int ic = valid ? i : 0;
    int r0 = row_off[ic];
    int r1 = valid ? row_off[ic + 1] : r0;
    // self row initializes accumulator set A (the +self term, exact)
    int4 sv = *reinterpret_cast<const int4*>(m2h + (size_t)ic * 64 + f8 * 8);
    const __half2* sh = reinterpret_cast<const __half2*>(&sv);
    __half2 a0 = sh[0], a1 = sh[1], a2 = sh[2], a3 = sh[3];
    __half2 z; z.x = __ushort_as_half((unsigned short)0); z.y = z.x;
    __half2 b0 = z, b1 = z, b2v_ = z, b3 = z;
    int j = r0;
    for (; j + 1 < r1; j += 2) {                   // 2 gathers in flight per group
        int s0 = csr_src[j], s1 = csr_src[j + 1];
        int4 v0 = *reinterpret_cast<const int4*>(m2h + (size_t)s0 * 64 + f8 * 8);
        int4 v1 = *reinterpret_cast<const int4*>(m2h + (size_t)s1 * 64 + f8 * 8);
        const __half2* h0 = reinterpret_cast<const __half2*>(&v0);
        const __half2* h1 = reinterpret_cast<const __half2*>(&v1);
        a0 = __hadd2(a0, h0[0]); a1 = __hadd2(a1, h0[1]);
        a2 = __hadd2(a2, h0[2]); a3 = __hadd2(a3, h0[3]);
        b0 = __hadd2(b0, h1[0]); b1 = __hadd2(b1, h1[1]);
        b2v_ = __hadd2(b2v_, h1[2]); b3 = __hadd2(b3, h1[3]);
    }
    if (j < r1) {                                  // odd tail
        int s0 = csr_src[j];
        int4 v0 = *reinterpret_cast<const int4*>(m2h + (size_t)s0 * 64 + f8 * 8);
        const __half2* h0 = reinterpret_cast<const __half2*>(&v0);
        a0 = __hadd2(a0, h0[0]); a1 = __hadd2(a1, h0[1]);
        a2 = __hadd2(a2, h0[2]); a3 = __hadd2(a3, h0[3]);
    }
    a0 = __hadd2(a0, b0); a1 = __hadd2(a1, b1);
    a2 = __hadd2(a2, b2v_); a3 = __hadd2(a3, b3);
    float2 f0 = __half22float2(a0), f1 = __half22float2(a1);
    float2 f2 = __half22float2(a2), f3 = __half22float2(a3);
    float di = dinv[ic];
    float4 b2a = reinterpret_cast<const float4*>(b2)[f8 * 2];
    float4 b2b = reinterpret_cast<const float4*>(b2)[f8 * 2 + 1];
    float4 wpa = reinterpret_cast<const float4*>(Wp)[f8 * 2];
    float4 wpb = reinterpret_cast<const float4*>(Wp)[f8 * 2 + 1];
    float v = fmaxf(fmaf(f0.x, di, b2a.x), 0.f) * wpa.x
            + fmaxf(fmaf(f0.y, di, b2a.y), 0.f) * wpa.y
            + fmaxf(fmaf(f1.x, di, b2a.z), 0.f) * wpa.z
            + fmaxf(fmaf(f1.y, di, b2a.w), 0.f) * wpa.w
            + fmaxf(fmaf(f2.x, di, b2b.x), 0.f) * wpb.x
            + fmaxf(fmaf(f2.y, di, b2b.y), 0.f) * wpb.y
            + fmaxf(fmaf(f3.x, di, b2b.z), 0.f) * wpb.z
            + fmaxf(fmaf(f3.y, di, b2b.w), 0.f) * wpb.w;
    v += __shfl_xor(v, 1);                         // reduce the 8-lane group
    v += __shfl_xor(v, 2);
    v += __shfl_xor(v, 4);
    if (valid && f8 == 0) out[i] = 1.f / (1.f + expf(-(v + bp[0])));
}

extern "C" void kernel_launch(void* const* d_in, const int* in_sizes, int n_in,
                              void* d_out, int out_size, void* d_ws, size_t ws_size,
                              hipStream_t stream) {
    const float* x  = (const float*)d_in[0];
    const int*   ei = (const int*)d_in[1];   // [2, E] int32
    const float* W1 = (const float*)d_in[2];
    const float* b1 = (const float*)d_in[3];
    const float* W2 = (const float*)d_in[4];
    const float* b2 = (const float*)d_in[5];
    const float* Wp = (const float*)d_in[6];
    const float* bp = (const float*)d_in[7];
    float* out = (float*)d_out;

    int n = in_sizes[0] / 2;
    int E = in_sizes[1] / 2;
    const int* src = ei;
    const int* dst = ei + E;

    char* ws = (char*)d_ws;
    size_t off = 0;
    auto alloc = [&](size_t bytes) -> void* {
        void* p = ws + off;
        off += (bytes + 255) & ~(size_t)255;
        return p;
    };
    int nb = (n + SCAN_EPB - 1) / SCAN_EPB;
    int*    deg     = (int*)alloc((size_t)n * 4);
    int*    bsum    = (int*)alloc((size_t)nb * 4);
    int*    row_off = (int*)alloc((size_t)(n + 1) * 4);
    int*    cursor  = (int*)alloc((size_t)n * 4);
    float*  dinv    = (float*)alloc((size_t)n * 4);
    float2* xsc     = (float2*)alloc((size_t)n * 8);
    float2* xam     = (float2*)alloc((size_t)n * 8);
    int*    csr_src = (int*)alloc((size_t)E * 4);
    __half* w2t     = (__half*)alloc((size_t)128 * 64 * 2);
    __half* m2h     = (__half*)alloc((size_t)n * 64 * 2);
    (void)ws_size;

    k_init     <<<256, 256, 0, stream>>>(W2, w2t, deg, n);
    k_deg      <<<(E + 255) / 256, 256, 0, stream>>>(dst, deg, E);
    k_blocksum <<<nb, SCAN_TPB, 0, stream>>>(deg, bsum, n);
    k_scanfinal<<<nb, SCAN_TPB, 0, stream>>>(deg, bsum, nb, row_off, cursor,
                                             (const float2*)x, dinv, xsc, n);
    k_fill     <<<(E + 255) / 256, 256, 0, stream>>>(src, dst, cursor, csr_src, E);
    k_agg1     <<<(n + 255) / 256, 256, 0, stream>>>(xsc, dinv, row_off, csr_src, xam, n);
    k_gemm1m   <<<(n + 63) / 64, 256, 0, stream>>>(xam, W1, b1, w2t, dinv, m2h, n);
    k_l2out    <<<(n + 31) / 32, 256, 0, stream>>>(m2h, dinv, row_off, csr_src,
                                                   b2, Wp, bp, out, n);
}